// Round 13
// baseline (124.791 us; speedup 1.0000x reference)
//
#include <hip/hip_runtime.h>
#include <hip/hip_bf16.h>

// MHA forward: b=2, s=2048, d=1024, h=16, dk=64. fp32 in/out, bf16 MFMA internally.
// ws layout (40.5 MB):
//   0      : xb [4096][1024] bf16 (8MB)  -- dead after gemm_qkv, reused as Ob (attn out)
//   8 MB   : Wqkvb [3072][1024] bf16 (6MB) -- dead after gemm_qkv, reused as P2 (4MB)
//   14 MB  : Wob [1024][1024] bf16 (2MB)
//   16 MB  : Qb [4096][1024] bf16 (8MB)  (RoPE'd, log2-domain scale)
//   24 MB  : Kb [4096][1024] bf16 (8MB)  (RoPE'd)
//   32 MB  : VbT [32 bh][64 dk][2048 seq] bf16 (8MB)
//   40 MB  : cosT/sinT (512KB) -- dead after gemm_qkv, reused as stats1/stats2

typedef __attribute__((ext_vector_type(8))) __bf16 bf16x8;
typedef __attribute__((ext_vector_type(4))) float f32x4;
typedef __attribute__((ext_vector_type(16))) float f32x16;
typedef __attribute__((ext_vector_type(4))) int int4v;
typedef __attribute__((ext_vector_type(2))) unsigned int uint2v;

#define MFMA16(a, b, c) __builtin_amdgcn_mfma_f32_16x16x32_bf16(a, b, c, 0, 0, 0)
#define MFMA32(a, b, c) __builtin_amdgcn_mfma_f32_32x32x16_bf16(a, b, c, 0, 0, 0)

__device__ inline unsigned short f2b(float f) {
  unsigned u = __builtin_bit_cast(unsigned, f);
  u = (u + 0x7FFF + ((u >> 16) & 1)) >> 16;   // RNE, finite inputs only
  return (unsigned short)u;
}

__device__ inline float b2f(unsigned short u) {
  return __builtin_bit_cast(float, ((unsigned)u) << 16);
}

__device__ inline unsigned pk2b(float lo, float hi) {
  return (unsigned)f2b(lo) | ((unsigned)f2b(hi) << 16);
}

__device__ inline unsigned cvtpk(float lo, float hi) {
  unsigned r;
  asm("v_cvt_pk_bf16_f32 %0, %1, %2" : "=v"(r) : "v"(lo), "v"(hi));
  return r;
}

__device__ inline void plswap(unsigned a, unsigned b, unsigned& o0, unsigned& o1) {
#if __has_builtin(__builtin_amdgcn_permlane32_swap)
  auto r = __builtin_amdgcn_permlane32_swap(a, b, false, false);
  o0 = r[0];
  o1 = r[1];
#else
  unsigned sa = (unsigned)__shfl_xor((int)a, 32, 64);
  unsigned sb = (unsigned)__shfl_xor((int)b, 32, 64);
  bool hi = (threadIdx.x & 32) != 0;
  o0 = hi ? sb : a;
  o1 = hi ? b : sa;
#endif
}

__device__ inline float fexp2(float x) {
#if __has_builtin(__builtin_amdgcn_exp2f)
  return __builtin_amdgcn_exp2f(x);
#else
  return exp2f(x);
#endif
}

// ---------------- fused prep ----------------

__device__ inline void cvt4(const float* __restrict__ s, unsigned short* __restrict__ d,
                            int i, float sc) {
  float4 v = *(const float4*)(s + i);
  uint2v p = {pk2b(v.x * sc, v.y * sc), pk2b(v.z * sc, v.w * sc)};
  *(uint2v*)(d + i) = p;
}

__global__ __launch_bounds__(256) void prep_kernel(
    const float* __restrict__ x, const float* __restrict__ Wq,
    const float* __restrict__ Wk, const float* __restrict__ Wv,
    const float* __restrict__ Wo, const int* __restrict__ tp,
    unsigned short* __restrict__ xb, unsigned short* __restrict__ Wqkvb,
    unsigned short* __restrict__ Wob, float* __restrict__ cosT,
    float* __restrict__ sinT) {
  int t = blockIdx.x * 256 + threadIdx.x;
  if (t < 1048576) {
    cvt4(x, xb, t * 4, 1.0f);
  } else if (t < 1310720) {
    cvt4(Wq, Wqkvb, (t - 1048576) * 4, 0.18033688f);   // (1/8)*log2(e)
  } else if (t < 1572864) {
    cvt4(Wk, Wqkvb + 1048576, (t - 1310720) * 4, 1.0f);
  } else if (t < 1835008) {
    cvt4(Wv, Wqkvb + 2097152, (t - 1572864) * 4, 1.0f);
  } else if (t < 2097152) {
    cvt4(Wo, Wob, (t - 1835008) * 4, 1.0f);
  } else {
    int base = (t - 2097152) * 4;
#pragma unroll
    for (int j = 0; j < 4; ++j) {
      int idx = base + j;
      int p = idx >> 5, i = idx & 31;
      float pos = (float)tp[p];
      float freq = powf(10000.0f, -(float)i / 32.0f);
      float ang = pos * freq;
      cosT[idx] = cosf(ang);
      sinT[idx] = sinf(ang);
    }
  }
}

// ---------------- GEMM staging (BK=64, xor-swizzled, B rows bit-permuted) ----------------

__device__ __forceinline__ void g_stage(const unsigned short* __restrict__ A,
                                        const unsigned short* __restrict__ B,
                                        unsigned short* __restrict__ As,
                                        unsigned short* __restrict__ Bs,
                                        int m0, int n0, int k0, int w, int lane) {
  const int srow = lane >> 3;
  const int schunk = (lane & 7) ^ srow;          // inverse swizzle on global source
#pragma unroll
  for (int c = 0; c < 4; ++c) {
    const int rb = w * 32 + c * 8;
    const unsigned short* ga = A + (size_t)(m0 + rb + srow) * 1024 + k0 + schunk * 8;
    __builtin_amdgcn_global_load_lds(
        (const __attribute__((address_space(1))) void*)ga,
        (__attribute__((address_space(3))) void*)(As + rb * 64), 16, 0, 0);
    const int rl = rb + srow;
    const int rB = n0 + (rl & 96) + ((rl & 15) << 1) + ((rl >> 4) & 1);
    const unsigned short* gb = B + (size_t)rB * 1024 + k0 + schunk * 8;
    __builtin_amdgcn_global_load_lds(
        (const __attribute__((address_space(1))) void*)gb,
        (__attribute__((address_space(3))) void*)(Bs + rb * 64), 16, 0, 0);
  }
}

// ---------------- GEMM 1: QKV projection + RoPE epilogue, 3-buf counted-vmcnt + slabs ----

__global__ __launch_bounds__(256) void gemm_qkv_kernel(
    const unsigned short* __restrict__ A,    // xb
    const unsigned short* __restrict__ B,    // Wqkvb
    unsigned short* __restrict__ Qb, unsigned short* __restrict__ Kb,
    unsigned short* __restrict__ VbT,        // [32][64][2048]
    const float* __restrict__ cosT, const float* __restrict__ sinT) {
  __shared__ unsigned short As[3][128 * 64];  // 3-deep pipeline, 96KB total
  __shared__ unsigned short Bs[3][128 * 64];
  // XCD slab remap: 8 XCDs = 4x2 slabs of 8m x 12n (per-XCD panel L2-friendly)
  const int bid = blockIdx.x;
  const int xcd = bid & 7, q = bid >> 3;         // q in [0,96)
  const int mg = xcd >> 1, ng = xcd & 1;
  const int m0 = (mg * 8 + (q & 7)) * 128;
  const int n0 = (ng * 12 + (q >> 3)) * 128;
  const int tid = threadIdx.x, w = tid >> 6, lane = tid & 63;
  const int l15 = lane & 15, l4 = lane >> 4;
  const int wr = w >> 1, wc = w & 1;

  f32x4 acc[4][4] = {};

  g_stage(A, B, As[0], Bs[0], m0, n0, 0, w, lane);
  g_stage(A, B, As[1], Bs[1], m0, n0, 64, w, lane);

  int ib = 0, is_ = 2;
  for (int k0 = 0; k0 < 1024; k0 += 64) {
    if (k0 < 960) {
      asm volatile("s_waitcnt vmcnt(8)" ::: "memory");   // oldest stage (this buf) done
    } else {
      asm volatile("s_waitcnt vmcnt(0)" ::: "memory");
    }
    __builtin_amdgcn_s_barrier();
    __builtin_amdgcn_sched_barrier(0);
    if (k0 + 128 < 1024)
      g_stage(A, B, As[is_], Bs[is_], m0, n0, k0 + 128, w, lane);

    const unsigned short* as = As[ib];
    const unsigned short* bs = Bs[ib];
#pragma unroll
    for (int kk = 0; kk < 2; ++kk) {
      bf16x8 af[4], bfr[4];
#pragma unroll
      for (int m = 0; m < 4; m++) {
        const int row = wr * 64 + m * 16 + l15;
        af[m] = *(const bf16x8*)(&as[row * 64 + (((kk * 4 + l4) ^ (l15 & 7)) * 8)]);
      }
#pragma unroll
      for (int n = 0; n < 4; n++) {
        const int row = wc * 64 + n * 16 + l15;
        bfr[n] = *(const bf16x8*)(&bs[row * 64 + (((kk * 4 + l4) ^ (l15 & 7)) * 8)]);
      }
#pragma unroll
      for (int m = 0; m < 4; m++)
#pragma unroll
        for (int n = 0; n < 4; n++)
          acc[m][n] = MFMA16(af[m], bfr[n], acc[m][n]);
    }
    ib = (ib == 2) ? 0 : ib + 1;
    is_ = (is_ == 2) ? 0 : is_ + 1;
  }

  const int cbase = n0 & 1023;
  if (n0 < 2048) {
    unsigned short* dst = (n0 < 1024) ? Qb : Kb;
#pragma unroll
    for (int m = 0; m < 4; m++) {
      const int row0 = m0 + wr * 64 + m * 16 + l4 * 4;
#pragma unroll
      for (int k = 0; k < 2; k++) {
        const int col = cbase + wc * 64 + k * 32 + 2 * l15;
        const int pi = k * 16 + l15;
#pragma unroll
        for (int r = 0; r < 4; r++) {
          const int pos = (row0 + r) & 2047;
          float c = cosT[pos * 32 + pi], s = sinT[pos * 32 + pi];
          float v0 = acc[m][2 * k][r], v1 = acc[m][2 * k + 1][r];
          float r1 = fmaf(v0, c, -v1 * s);
          float r2 = fmaf(v1, c, v0 * s);
          *(unsigned*)(dst + (size_t)(row0 + r) * 1024 + col) = pk2b(r1, r2);
        }
      }
    }
  } else {
#pragma unroll
    for (int m = 0; m < 4; m++) {
      const int row0 = m0 + wr * 64 + m * 16 + l4 * 4;
      const int bb = row0 >> 11, seq = row0 & 2047;
#pragma unroll
      for (int k = 0; k < 2; k++) {
        const int dkg = cbase + wc * 64 + k * 32 + 2 * l15;
        const int h = dkg >> 6, dk = dkg & 63;
        unsigned short* vp = VbT + (size_t)(bb * 16 + h) * 131072 + dk * 2048 + seq;
        uint2v e = {pk2b(acc[m][2 * k][0], acc[m][2 * k][1]),
                    pk2b(acc[m][2 * k][2], acc[m][2 * k][3])};
        *(uint2v*)vp = e;
        uint2v o = {pk2b(acc[m][2 * k + 1][0], acc[m][2 * k + 1][1]),
                    pk2b(acc[m][2 * k + 1][2], acc[m][2 * k + 1][3])};
        *(uint2v*)(vp + 2048) = o;
      }
    }
  }
}

// ---------------- GEMM 2: output projection, 3-buf counted-vmcnt pipeline ----------------

__global__ __launch_bounds__(256) void gemm_out_kernel(
    const unsigned short* __restrict__ A,    // Ob [4096][1024]
    const unsigned short* __restrict__ B,    // Wob [1024][1024]
    float* __restrict__ out) {
  __shared__ unsigned short As[3][128 * 64];
  __shared__ unsigned short Bs[3][128 * 64];
  const int bid = blockIdx.x;
  const int sw = (bid & 7) * 32 + (bid >> 3);
  const int n0 = (sw % 8) * 128, m0 = (sw / 8) * 128;
  const int tid = threadIdx.x, w = tid >> 6, lane = tid & 63;
  const int l15 = lane & 15, l4 = lane >> 4;
  const int wr = w >> 1, wc = w & 1;

  f32x4 acc[4][4] = {};

  g_stage(A, B, As[0], Bs[0], m0, n0, 0, w, lane);
  g_stage(A, B, As[1], Bs[1], m0, n0, 64, w, lane);

  int ib = 0, is_ = 2;
  for (int k0 = 0; k0 < 1024; k0 += 64) {
    if (k0 < 960) {
      asm volatile("s_waitcnt vmcnt(8)" ::: "memory");
    } else {
      asm volatile("s_waitcnt vmcnt(0)" ::: "memory");
    }
    __builtin_amdgcn_s_barrier();
    __builtin_amdgcn_sched_barrier(0);
    if (k0 + 128 < 1024)
      g_stage(A, B, As[is_], Bs[is_], m0, n0, k0 + 128, w, lane);

    const unsigned short* as = As[ib];
    const unsigned short* bs = Bs[ib];
#pragma unroll
    for (int kk = 0; kk < 2; ++kk) {
      bf16x8 af[4], bfr[4];
#pragma unroll
      for (int m = 0; m < 4; m++) {
        const int row = wr * 64 + m * 16 + l15;
        af[m] = *(const bf16x8*)(&as[row * 64 + (((kk * 4 + l4) ^ (l15 & 7)) * 8)]);
      }
#pragma unroll
      for (int n = 0; n < 4; n++) {
        const int row = wc * 64 + n * 16 + l15;
        bfr[n] = *(const bf16x8*)(&bs[row * 64 + (((kk * 4 + l4) ^ (l15 & 7)) * 8)]);
      }
#pragma unroll
      for (int m = 0; m < 4; m++)
#pragma unroll
        for (int n = 0; n < 4; n++)
          acc[m][n] = MFMA16(af[m], bfr[n], acc[m][n]);
    }
    ib = (ib == 2) ? 0 : ib + 1;
    is_ = (is_ == 2) ? 0 : is_ + 1;
  }

#pragma unroll
  for (int m = 0; m < 4; m++) {
    const int row0 = m0 + wr * 64 + m * 16 + l4 * 4;
#pragma unroll
    for (int k = 0; k < 2; k++) {
      const int col = n0 + wc * 64 + k * 32 + 2 * l15;
#pragma unroll
      for (int r = 0; r < 4; r++) {
        float2 v = {acc[m][2 * k][r], acc[m][2 * k + 1][r]};
        *(float2*)(out + (size_t)(row0 + r) * 1024 + col) = v;
      }
    }
  }
}

// ---------------- Flash attention: 512 equal 17-tile blocks + LSE merge ----------------

__device__ __forceinline__ void stage_tiles(const unsigned short* __restrict__ Kgb,
                                            const unsigned short* __restrict__ Vgb,
                                            unsigned short* KsBuf, unsigned short* VsBuf,
                                            int kv0, int w, int lane) {
#pragma unroll
  for (int c = 0; c < 2; ++c) {
    const int rowbase = w * 16 + c * 8;
    const int row = rowbase + (lane >> 3);
    const int chunk = (lane & 7) ^ (lane >> 3);    // inverse swizzle on global source
    const unsigned short* gk = Kgb + (size_t)(kv0 + row) * 1024 + chunk * 8;
    __builtin_amdgcn_global_load_lds(
        (const __attribute__((address_space(1))) void*)gk,
        (__attribute__((address_space(3))) void*)(KsBuf + rowbase * 64), 16, 0, 0);
    const unsigned short* gv = Vgb + (size_t)row * 2048 + kv0 + chunk * 8;
    __builtin_amdgcn_global_load_lds(
        (const __attribute__((address_space(1))) void*)gv,
        (__attribute__((address_space(3))) void*)(VsBuf + rowbase * 64), 16, 0, 0);
  }
}

__device__ __forceinline__ void attn_stream(
    int qt, int t0, int t1, bool finalize,
    int b, int h, int w, int lane,
    const unsigned short* __restrict__ Qb,
    const unsigned short* __restrict__ Kgb,
    const unsigned short* __restrict__ Vgb,
    unsigned short* __restrict__ outBase, int ostride,
    float* __restrict__ statsOut,
    unsigned short (*Ks)[64 * 64], unsigned short (*Vs)[64 * 64]) {
  const int l31 = lane & 31, l32 = lane >> 5;
  const int sw = l31 & 7;

  const unsigned short* qptr =
      Qb + (size_t)(b * 2048 + qt * 128 + w * 32 + l31) * 1024 + h * 64 + l32 * 8;
  bf16x8 qa[4];
#pragma unroll
  for (int kk = 0; kk < 4; ++kk) qa[kk] = *(const bf16x8*)(qptr + kk * 16);

  f32x16 oacc[2] = {};
  float m = -3e38f, l = 0.f;

  stage_tiles(Kgb, Vgb, Ks[0], Vs[0], t0 * 64, w, lane);
  stage_tiles(Kgb, Vgb, Ks[1], Vs[1], (t0 + 1) * 64, w, lane);

  int ib = 0, is_ = 2;
  for (int t = t0; t < t1; ++t) {
    if (t < t1 - 1) {
      asm volatile("s_waitcnt vmcnt(4)" ::: "memory");
    } else {
      asm volatile("s_waitcnt vmcnt(0)" ::: "memory");
    }
    __builtin_amdgcn_s_barrier();
    __builtin_amdgcn_sched_barrier(0);
    if (t + 2 < t1)
      stage_tiles(Kgb, Vgb, Ks[is_], Vs[is_], (t + 2) * 64, w, lane);

    // QK^T swapped: St = mfma32(K_frag, Q_frag) -> S^T[kv][q], q = l31
    const char* ksb = (const char*)Ks[ib];
    f32x16 st[2];
    __builtin_amdgcn_s_setprio(1);
#pragma unroll
    for (int f = 0; f < 2; ++f) {
      const char* kb = ksb + (f * 32 + l31) * 128;
      f32x16 z = {};
#pragma unroll
      for (int kk = 0; kk < 4; ++kk) {
        bf16x8 kf = *(const bf16x8*)(kb + ((((kk << 1) | l32) ^ sw) * 16));
        z = MFMA32(kf, qa[kk], z);
      }
      st[f] = z;
    }
    __builtin_amdgcn_s_setprio(0);

    // causal mask (diagonal tiles only; prefix streams never trigger this)
    if (t >= 2 * qt + (w >> 1)) {
      const int qg = qt * 128 + w * 32 + l31;
      const int kvb = t * 64 + 4 * l32;
#pragma unroll
      for (int f = 0; f < 2; ++f)
#pragma unroll
        for (int reg = 0; reg < 16; ++reg) {
          int kv = kvb + 32 * f + (reg & 3) + 8 * (reg >> 2);
          if (kv > qg) st[f][reg] = -3e38f;
        }
    }

    // row max: in-register tree + 1 swap across lane halves
    float a8[8];
#pragma unroll
    for (int j = 0; j < 8; ++j)
      a8[j] = fmaxf(fmaxf(st[0][j], st[0][j + 8]), fmaxf(st[1][j], st[1][j + 8]));
    float pm = fmaxf(fmaxf(fmaxf(a8[0], a8[1]), fmaxf(a8[2], a8[3])),
                     fmaxf(fmaxf(a8[4], a8[5]), fmaxf(a8[6], a8[7])));
    pm = fmaxf(pm, __shfl_xor(pm, 32, 64));

    // defer-max: rescale only when running max grew by > 8 (log2 domain)
    if (!__all(pm - m <= 8.0f)) {
      float mn = fmaxf(m, pm);
      float al = fexp2(m - mn);
      l *= al;
#pragma unroll
      for (int df = 0; df < 2; ++df)
#pragma unroll
        for (int reg = 0; reg < 16; ++reg) oacc[df][reg] *= al;
      m = mn;
    }

    // p = exp2(s - m), pack to bf16 pairs
    unsigned pku[2][4][2];
    float rs0 = 0.f, rs1 = 0.f;
#pragma unroll
    for (int f = 0; f < 2; ++f)
#pragma unroll
      for (int rr = 0; rr < 4; ++rr)
#pragma unroll
        for (int i = 0; i < 2; ++i) {
          float p0 = fexp2(st[f][4 * rr + 2 * i] - m);
          float p1 = fexp2(st[f][4 * rr + 2 * i + 1] - m);
          rs0 += p0; rs1 += p1;
          pku[f][rr][i] = cvtpk(p0, p1);
        }
    float rs = rs0 + rs1;
    rs += __shfl_xor(rs, 32, 64);
    l += rs;

    // redistribute P^T into B-operand frags via permlane32_swap
    union FB { unsigned u[4]; bf16x8 v; };
    FB pfrag[4];
#pragma unroll
    for (int kk = 0; kk < 4; ++kk) {
      const int f = kk >> 1, kl = kk & 1;
      unsigned o00, o10, o01, o11;
      plswap(pku[f][2 * kl][0], pku[f][2 * kl + 1][0], o00, o10);
      plswap(pku[f][2 * kl][1], pku[f][2 * kl + 1][1], o01, o11);
      pfrag[kk].u[0] = o00; pfrag[kk].u[1] = o01;
      pfrag[kk].u[2] = o10; pfrag[kk].u[3] = o11;
    }

    // PV swapped: O^T[d][q] += mfma32(V^T_frag, P^T_frag)
    const char* vsb = (const char*)Vs[ib];
    __builtin_amdgcn_s_setprio(1);
#pragma unroll
    for (int df = 0; df < 2; ++df) {
      const char* vb = vsb + (df * 32 + l31) * 128;
#pragma unroll
      for (int kk = 0; kk < 4; ++kk) {
        bf16x8 vf = *(const bf16x8*)(vb + ((((kk << 1) | l32) ^ sw) * 16));
        oacc[df] = MFMA32(vf, pfrag[kk].v, oacc[df]);
      }
    }
    __builtin_amdgcn_s_setprio(0);

    ib = (ib == 2) ? 0 : ib + 1;
    is_ = (is_ == 2) ? 0 : is_ + 1;
  }

  // output: normalized (final) or raw partial (unnormalized) + stats
  const float sc = finalize ? (1.0f / l) : 1.0f;
  unsigned short* ob = outBase + (size_t)(w * 32 + l31) * ostride + 4 * l32;
#pragma unroll
  for (int df = 0; df < 2; ++df)
#pragma unroll
    for (int rr = 0; rr < 4; ++rr)
#pragma unroll
      for (int i = 0; i < 2; ++i) {
        *(unsigned*)(ob + df * 32 + rr * 8 + 2 * i) =
            pk2b(oacc[df][4 * rr + 2 * i] * sc, oacc[df][4 * rr + 2 * i + 1] * sc);
      }
  if (!finalize && l32 == 0) {
    float2 st2 = {m, l};
    *(float2*)(statsOut + (w * 32 + l31) * 2) = st2;
  }
}

__global__ __launch_bounds__(256, 2) void attn_kernel(
    const unsigned short* __restrict__ Qb,
    const unsigned short* __restrict__ Kb,
    const unsigned short* __restrict__ VbT,   // [32][64][2048]
    unsigned short* __restrict__ Ob,
    unsigned short* __restrict__ P2,          // [256][128][64] partial2
    float* __restrict__ stats1, float* __restrict__ stats2) {
  __shared__ unsigned short Ks[3][64 * 64];
  __shared__ unsigned short Vs[3][64 * 64];
  const int bh = blockIdx.x;                  // fastest -> same bh lands on one XCD
  const int y = blockIdx.y;                   // 0..15
  const int j = y >> 1, half = y & 1;
  const int b = bh >> 4, h = bh & 15;
  const int qtB = 15 - j;
  const int x = 15 - 2 * j;                   // split point of big chunk
  const int cid = bh * 8 + j;
  const int tid = threadIdx.x, w = tid >> 6, lane = tid & 63;

  const unsigned short* Kgb = Kb + (size_t)b * 2048 * 1024 + h * 64;
  const unsigned short* Vgb = VbT + (size_t)bh * 131072;

  if (half == 0) {
    // prefix of big chunk -> unnormalized partial1 into Ob slot + stats1
    attn_stream(qtB, 0, x, false, b, h, w, lane, Qb, Kgb, Vgb,
                Ob + (size_t)(b * 2048 + qtB * 128) * 1024 + h * 64, 1024,
                stats1 + cid * 256, Ks, Vs);
    __syncthreads();
    // whole small chunk -> final
    attn_stream(j, 0, 2 * j + 2, true, b, h, w, lane, Qb, Kgb, Vgb,
                Ob + (size_t)(b * 2048 + j * 128) * 1024 + h * 64, 1024,
                nullptr, Ks, Vs);
  } else {
    // remainder of big chunk -> unnormalized partial2 into P2 + stats2
    attn_stream(qtB, x, 32 - 2 * j, false, b, h, w, lane, Qb, Kgb, Vgb,
                P2 + (size_t)cid * 8192, 64,
                stats2 + cid * 256, Ks, Vs);
  }
}

// ---------------- merge: LSE-combine split big chunks ----------------

__global__ __launch_bounds__(256) void merge_kernel(
    unsigned short* __restrict__ Ob, const unsigned short* __restrict__ P2,
    const float* __restrict__ stats1, const float* __restrict__ stats2) {
  const int cid = blockIdx.x;                 // 256
  const int bh = cid >> 3, j = cid & 7, qt = 15 - j;
  const int b = bh >> 4, h = bh & 15;
  const int tid = threadIdx.x;
  const int r = tid >> 1, ch = (tid & 1) * 32;

  const float m1 = stats1[cid * 256 + r * 2], l1 = stats1[cid * 256 + r * 2 + 1];
  const float m2 = stats2[cid * 256 + r * 2], l2 = stats2[cid * 256 + r * 2 + 1];
  const float M = fmaxf(m1, m2);
  const float a1 = fexp2(m1 - M), a2 = fexp2(m2 - M);
  const float invL = 1.0f / (l1 * a1 + l2 * a2);
  const float c1 = a1 * invL, c2 = a2 * invL;

  unsigned short* o1 = Ob + (size_t)(b * 2048 + qt * 128 + r) * 1024 + h * 64 + ch;
  const unsigned short* o2 = P2 + (size_t)cid * 8192 + r * 64 + ch;
#pragma unroll
  for (int i = 0; i < 32; i += 8) {
    int4v v1 = *(const int4v*)(o1 + i);
    int4v v2 = *(const int4v*)(o2 + i);
    int4v ro;
#pragma unroll
    for (int k = 0; k < 4; ++k) {
      unsigned u1 = (unsigned)v1[k], u2 = (unsigned)v2[k];
      float lo = b2f((unsigned short)u1) * c1 + b2f((unsigned short)u2) * c2;
      float hi = b2f((unsigned short)(u1 >> 16)) * c1 + b2f((unsigned short)(u2 >> 16)) * c2;
      ro[k] = (int)pk2b(lo, hi);
    }
    *(int4v*)(o1 + i) = ro;
  }
}

// ---------------- launch ----------------

extern "C" void kernel_launch(void* const* d_in, const int* in_sizes, int n_in,
                              void* d_out, int out_size, void* d_ws, size_t ws_size,
                              hipStream_t stream) {
  (void)in_sizes; (void)n_in; (void)out_size; (void)ws_size;
  const float* x  = (const float*)d_in[0];
  const int*  tp  = (const int*)d_in[1];
  const float* Wq = (const float*)d_in[2];
  const float* Wk = (const float*)d_in[3];
  const float* Wv = (const float*)d_in[4];
  const float* Wo = (const float*)d_in[5];
  float* out = (float*)d_out;

  char* ws = (char*)d_ws;
  unsigned short* xb    = (unsigned short*)(ws);                       // 8MB
  unsigned short* Ob    = (unsigned short*)(ws);                       // reuses xb
  unsigned short* Wqkvb = (unsigned short*)(ws + (8ull << 20));        // 6MB
  unsigned short* P2    = (unsigned short*)(ws + (8ull << 20));        // reuses Wqkvb (4MB)
  unsigned short* Wob   = (unsigned short*)(ws + (14ull << 20));       // 2MB
  unsigned short* Qb    = (unsigned short*)(ws + (16ull << 20));       // 8MB
  unsigned short* Kb    = (unsigned short*)(ws + (24ull << 20));       // 8MB
  unsigned short* VbT   = (unsigned short*)(ws + (32ull << 20));       // 8MB
  float* cosT   = (float*)(ws + (40ull << 20));                        // 256KB
  float* sinT   = (float*)(ws + (40ull << 20) + 262144);               // 256KB
  float* stats1 = (float*)(ws + (40ull << 20));                        // reuses cosT
  float* stats2 = (float*)(ws + (40ull << 20) + 262144);               // reuses sinT

  prep_kernel<<<8256, 256, 0, stream>>>(x, Wq, Wk, Wv, Wo, tp, xb, Wqkvb, Wob, cosT, sinT);
  gemm_qkv_kernel<<<768, 256, 0, stream>>>(xb, Wqkvb, Qb, Kb, VbT, cosT, sinT);
  attn_kernel<<<dim3(32, 16), 256, 0, stream>>>(Qb, Kb, VbT, Ob, P2, stats1, stats2);
  merge_kernel<<<256, 256, 0, stream>>>(Ob, P2, stats1, stats2);
  gemm_out_kernel<<<256, 256, 0, stream>>>(Ob, Wob, out);
}

// Round 14
// 113.378 us; speedup vs baseline: 1.1007x; 1.1007x over previous
//
#include <hip/hip_runtime.h>
#include <hip/hip_bf16.h>

// MHA forward: b=2, s=2048, d=1024, h=16, dk=64. fp32 in/out, bf16 MFMA internally.
// ws layout (40.5 MB):
//   0      : xb [4096][1024] bf16 (8MB)  -- dead after gemm_qkv, reused as Ob (attn out)
//   8 MB   : Wqkvb [3072][1024] bf16 (6MB) -- dead after gemm_qkv, reused as P2 (4MB)
//   14 MB  : Wob [1024][1024] bf16 (2MB)
//   16 MB  : Qb [4096][1024] bf16 (8MB)  (RoPE'd, log2-domain scale)
//   24 MB  : Kb [4096][1024] bf16 (8MB)  (RoPE'd)
//   32 MB  : VbT [32 bh][64 dk][2048 seq] bf16 (8MB)
//   40 MB  : cosT/sinT (512KB) -- dead after gemm_qkv, reused as stats1/stats2

typedef __attribute__((ext_vector_type(8))) __bf16 bf16x8;
typedef __attribute__((ext_vector_type(4))) float f32x4;
typedef __attribute__((ext_vector_type(16))) float f32x16;
typedef __attribute__((ext_vector_type(4))) int int4v;
typedef __attribute__((ext_vector_type(2))) unsigned int uint2v;

#define MFMA16(a, b, c) __builtin_amdgcn_mfma_f32_16x16x32_bf16(a, b, c, 0, 0, 0)
#define MFMA32(a, b, c) __builtin_amdgcn_mfma_f32_32x32x16_bf16(a, b, c, 0, 0, 0)

__device__ inline unsigned short f2b(float f) {
  unsigned u = __builtin_bit_cast(unsigned, f);
  u = (u + 0x7FFF + ((u >> 16) & 1)) >> 16;   // RNE, finite inputs only
  return (unsigned short)u;
}

__device__ inline float b2f(unsigned short u) {
  return __builtin_bit_cast(float, ((unsigned)u) << 16);
}

__device__ inline unsigned pk2b(float lo, float hi) {
  return (unsigned)f2b(lo) | ((unsigned)f2b(hi) << 16);
}

__device__ inline unsigned cvtpk(float lo, float hi) {
  unsigned r;
  asm("v_cvt_pk_bf16_f32 %0, %1, %2" : "=v"(r) : "v"(lo), "v"(hi));
  return r;
}

__device__ inline void plswap(unsigned a, unsigned b, unsigned& o0, unsigned& o1) {
#if __has_builtin(__builtin_amdgcn_permlane32_swap)
  auto r = __builtin_amdgcn_permlane32_swap(a, b, false, false);
  o0 = r[0];
  o1 = r[1];
#else
  unsigned sa = (unsigned)__shfl_xor((int)a, 32, 64);
  unsigned sb = (unsigned)__shfl_xor((int)b, 32, 64);
  bool hi = (threadIdx.x & 32) != 0;
  o0 = hi ? sb : a;
  o1 = hi ? b : sa;
#endif
}

__device__ inline float fexp2(float x) {
#if __has_builtin(__builtin_amdgcn_exp2f)
  return __builtin_amdgcn_exp2f(x);
#else
  return exp2f(x);
#endif
}

// ---------------- fused prep ----------------

__device__ inline void cvt4(const float* __restrict__ s, unsigned short* __restrict__ d,
                            int i, float sc) {
  float4 v = *(const float4*)(s + i);
  uint2v p = {pk2b(v.x * sc, v.y * sc), pk2b(v.z * sc, v.w * sc)};
  *(uint2v*)(d + i) = p;
}

__global__ __launch_bounds__(256) void prep_kernel(
    const float* __restrict__ x, const float* __restrict__ Wq,
    const float* __restrict__ Wk, const float* __restrict__ Wv,
    const float* __restrict__ Wo, const int* __restrict__ tp,
    unsigned short* __restrict__ xb, unsigned short* __restrict__ Wqkvb,
    unsigned short* __restrict__ Wob, float* __restrict__ cosT,
    float* __restrict__ sinT) {
  int t = blockIdx.x * 256 + threadIdx.x;
  if (t < 1048576) {
    cvt4(x, xb, t * 4, 1.0f);
  } else if (t < 1310720) {
    cvt4(Wq, Wqkvb, (t - 1048576) * 4, 0.18033688f);   // (1/8)*log2(e)
  } else if (t < 1572864) {
    cvt4(Wk, Wqkvb + 1048576, (t - 1310720) * 4, 1.0f);
  } else if (t < 1835008) {
    cvt4(Wv, Wqkvb + 2097152, (t - 1572864) * 4, 1.0f);
  } else if (t < 2097152) {
    cvt4(Wo, Wob, (t - 1835008) * 4, 1.0f);
  } else {
    int base = (t - 2097152) * 4;
#pragma unroll
    for (int j = 0; j < 4; ++j) {
      int idx = base + j;
      int p = idx >> 5, i = idx & 31;
      float pos = (float)tp[p];
      float freq = powf(10000.0f, -(float)i / 32.0f);
      float ang = pos * freq;
      cosT[idx] = cosf(ang);
      sinT[idx] = sinf(ang);
    }
  }
}

// ---------------- GEMM staging (BK=64, xor-swizzled, B rows bit-permuted) ----------------

__device__ __forceinline__ void g_stage(const unsigned short* __restrict__ A,
                                        const unsigned short* __restrict__ B,
                                        unsigned short* __restrict__ As,
                                        unsigned short* __restrict__ Bs,
                                        int m0, int n0, int k0, int w, int lane) {
  const int srow = lane >> 3;
  const int schunk = (lane & 7) ^ srow;          // inverse swizzle on global source
#pragma unroll
  for (int c = 0; c < 4; ++c) {
    const int rb = w * 32 + c * 8;
    const unsigned short* ga = A + (size_t)(m0 + rb + srow) * 1024 + k0 + schunk * 8;
    __builtin_amdgcn_global_load_lds(
        (const __attribute__((address_space(1))) void*)ga,
        (__attribute__((address_space(3))) void*)(As + rb * 64), 16, 0, 0);
    const int rl = rb + srow;
    const int rB = n0 + (rl & 96) + ((rl & 15) << 1) + ((rl >> 4) & 1);
    const unsigned short* gb = B + (size_t)rB * 1024 + k0 + schunk * 8;
    __builtin_amdgcn_global_load_lds(
        (const __attribute__((address_space(1))) void*)gb,
        (__attribute__((address_space(3))) void*)(Bs + rb * 64), 16, 0, 0);
  }
}

// ---------------- GEMM 1: QKV projection + RoPE epilogue ----------------
// 2-buf counted-vmcnt pipeline: barrier -> issue stage(k+1) -> vmcnt(8) -> compute(k).
// Loads are never drained to 0 mid-loop (T4); 64KB LDS keeps 2 blocks/CU.

__global__ __launch_bounds__(256) void gemm_qkv_kernel(
    const unsigned short* __restrict__ A,    // xb
    const unsigned short* __restrict__ B,    // Wqkvb
    unsigned short* __restrict__ Qb, unsigned short* __restrict__ Kb,
    unsigned short* __restrict__ VbT,        // [32][64][2048]
    const float* __restrict__ cosT, const float* __restrict__ sinT) {
  __shared__ unsigned short As[2][128 * 64];
  __shared__ unsigned short Bs[2][128 * 64];
  // XCD slab remap: 8 XCDs = 4x2 slabs of 8m x 12n (per-XCD panel L2-friendly)
  const int bid = blockIdx.x;
  const int xcd = bid & 7, q = bid >> 3;         // q in [0,96)
  const int mg = xcd >> 1, ng = xcd & 1;
  const int m0 = (mg * 8 + (q & 7)) * 128;
  const int n0 = (ng * 12 + (q >> 3)) * 128;
  const int tid = threadIdx.x, w = tid >> 6, lane = tid & 63;
  const int l15 = lane & 15, l4 = lane >> 4;
  const int wr = w >> 1, wc = w & 1;

  f32x4 acc[4][4] = {};

  g_stage(A, B, As[0], Bs[0], m0, n0, 0, w, lane);   // 8 loads in flight

  int cur = 0;
  for (int k0 = 0; k0 < 1024; k0 += 64) {
    __builtin_amdgcn_s_barrier();                    // readers of buf[cur^1] done
    if (k0 + 64 < 1024) {
      g_stage(A, B, As[cur ^ 1], Bs[cur ^ 1], m0, n0, k0 + 64, w, lane);
      asm volatile("s_waitcnt vmcnt(8)" ::: "memory");   // stage(k) landed; stage(k+1) flies
    } else {
      asm volatile("s_waitcnt vmcnt(0)" ::: "memory");
    }
    __builtin_amdgcn_sched_barrier(0);

    const unsigned short* as = As[cur];
    const unsigned short* bs = Bs[cur];
#pragma unroll
    for (int kk = 0; kk < 2; ++kk) {
      bf16x8 af[4], bfr[4];
#pragma unroll
      for (int m = 0; m < 4; m++) {
        const int row = wr * 64 + m * 16 + l15;
        af[m] = *(const bf16x8*)(&as[row * 64 + (((kk * 4 + l4) ^ (l15 & 7)) * 8)]);
      }
#pragma unroll
      for (int n = 0; n < 4; n++) {
        const int row = wc * 64 + n * 16 + l15;
        bfr[n] = *(const bf16x8*)(&bs[row * 64 + (((kk * 4 + l4) ^ (l15 & 7)) * 8)]);
      }
#pragma unroll
      for (int m = 0; m < 4; m++)
#pragma unroll
        for (int n = 0; n < 4; n++)
          acc[m][n] = MFMA16(af[m], bfr[n], acc[m][n]);
    }
    cur ^= 1;
  }

  const int cbase = n0 & 1023;
  if (n0 < 2048) {
    unsigned short* dst = (n0 < 1024) ? Qb : Kb;
#pragma unroll
    for (int m = 0; m < 4; m++) {
      const int row0 = m0 + wr * 64 + m * 16 + l4 * 4;
#pragma unroll
      for (int k = 0; k < 2; k++) {
        const int col = cbase + wc * 64 + k * 32 + 2 * l15;
        const int pi = k * 16 + l15;
#pragma unroll
        for (int r = 0; r < 4; r++) {
          const int pos = (row0 + r) & 2047;
          float c = cosT[pos * 32 + pi], s = sinT[pos * 32 + pi];
          float v0 = acc[m][2 * k][r], v1 = acc[m][2 * k + 1][r];
          float r1 = fmaf(v0, c, -v1 * s);
          float r2 = fmaf(v1, c, v0 * s);
          *(unsigned*)(dst + (size_t)(row0 + r) * 1024 + col) = pk2b(r1, r2);
        }
      }
    }
  } else {
#pragma unroll
    for (int m = 0; m < 4; m++) {
      const int row0 = m0 + wr * 64 + m * 16 + l4 * 4;
      const int bb = row0 >> 11, seq = row0 & 2047;
#pragma unroll
      for (int k = 0; k < 2; k++) {
        const int dkg = cbase + wc * 64 + k * 32 + 2 * l15;
        const int h = dkg >> 6, dk = dkg & 63;
        unsigned short* vp = VbT + (size_t)(bb * 16 + h) * 131072 + dk * 2048 + seq;
        uint2v e = {pk2b(acc[m][2 * k][0], acc[m][2 * k][1]),
                    pk2b(acc[m][2 * k][2], acc[m][2 * k][3])};
        *(uint2v*)vp = e;
        uint2v o = {pk2b(acc[m][2 * k + 1][0], acc[m][2 * k + 1][1]),
                    pk2b(acc[m][2 * k + 1][2], acc[m][2 * k + 1][3])};
        *(uint2v*)(vp + 2048) = o;
      }
    }
  }
}

// ---------------- GEMM 2: output projection, same counted-vmcnt 2-buf pipeline ----------

__global__ __launch_bounds__(256) void gemm_out_kernel(
    const unsigned short* __restrict__ A,    // Ob [4096][1024]
    const unsigned short* __restrict__ B,    // Wob [1024][1024]
    float* __restrict__ out) {
  __shared__ unsigned short As[2][128 * 64];
  __shared__ unsigned short Bs[2][128 * 64];
  const int bid = blockIdx.x;
  const int sw = (bid & 7) * 32 + (bid >> 3);
  const int n0 = (sw % 8) * 128, m0 = (sw / 8) * 128;
  const int tid = threadIdx.x, w = tid >> 6, lane = tid & 63;
  const int l15 = lane & 15, l4 = lane >> 4;
  const int wr = w >> 1, wc = w & 1;

  f32x4 acc[4][4] = {};

  g_stage(A, B, As[0], Bs[0], m0, n0, 0, w, lane);

  int cur = 0;
  for (int k0 = 0; k0 < 1024; k0 += 64) {
    __builtin_amdgcn_s_barrier();
    if (k0 + 64 < 1024) {
      g_stage(A, B, As[cur ^ 1], Bs[cur ^ 1], m0, n0, k0 + 64, w, lane);
      asm volatile("s_waitcnt vmcnt(8)" ::: "memory");
    } else {
      asm volatile("s_waitcnt vmcnt(0)" ::: "memory");
    }
    __builtin_amdgcn_sched_barrier(0);

    const unsigned short* as = As[cur];
    const unsigned short* bs = Bs[cur];
#pragma unroll
    for (int kk = 0; kk < 2; ++kk) {
      bf16x8 af[4], bfr[4];
#pragma unroll
      for (int m = 0; m < 4; m++) {
        const int row = wr * 64 + m * 16 + l15;
        af[m] = *(const bf16x8*)(&as[row * 64 + (((kk * 4 + l4) ^ (l15 & 7)) * 8)]);
      }
#pragma unroll
      for (int n = 0; n < 4; n++) {
        const int row = wc * 64 + n * 16 + l15;
        bfr[n] = *(const bf16x8*)(&bs[row * 64 + (((kk * 4 + l4) ^ (l15 & 7)) * 8)]);
      }
#pragma unroll
      for (int m = 0; m < 4; m++)
#pragma unroll
        for (int n = 0; n < 4; n++)
          acc[m][n] = MFMA16(af[m], bfr[n], acc[m][n]);
    }
    cur ^= 1;
  }

#pragma unroll
  for (int m = 0; m < 4; m++) {
    const int row0 = m0 + wr * 64 + m * 16 + l4 * 4;
#pragma unroll
    for (int k = 0; k < 2; k++) {
      const int col = n0 + wc * 64 + k * 32 + 2 * l15;
#pragma unroll
      for (int r = 0; r < 4; r++) {
        float2 v = {acc[m][2 * k][r], acc[m][2 * k + 1][r]};
        *(float2*)(out + (size_t)(row0 + r) * 1024 + col) = v;
      }
    }
  }
}

// ---------------- Flash attention: 512 equal 17-tile blocks + LSE merge ----------------

__device__ __forceinline__ void stage_tiles(const unsigned short* __restrict__ Kgb,
                                            const unsigned short* __restrict__ Vgb,
                                            unsigned short* KsBuf, unsigned short* VsBuf,
                                            int kv0, int w, int lane) {
#pragma unroll
  for (int c = 0; c < 2; ++c) {
    const int rowbase = w * 16 + c * 8;
    const int row = rowbase + (lane >> 3);
    const int chunk = (lane & 7) ^ (lane >> 3);    // inverse swizzle on global source
    const unsigned short* gk = Kgb + (size_t)(kv0 + row) * 1024 + chunk * 8;
    __builtin_amdgcn_global_load_lds(
        (const __attribute__((address_space(1))) void*)gk,
        (__attribute__((address_space(3))) void*)(KsBuf + rowbase * 64), 16, 0, 0);
    const unsigned short* gv = Vgb + (size_t)row * 2048 + kv0 + chunk * 8;
    __builtin_amdgcn_global_load_lds(
        (const __attribute__((address_space(1))) void*)gv,
        (__attribute__((address_space(3))) void*)(VsBuf + rowbase * 64), 16, 0, 0);
  }
}

__device__ __forceinline__ void attn_stream(
    int qt, int t0, int t1, bool finalize,
    int b, int h, int w, int lane,
    const unsigned short* __restrict__ Qb,
    const unsigned short* __restrict__ Kgb,
    const unsigned short* __restrict__ Vgb,
    unsigned short* __restrict__ outBase, int ostride,
    float* __restrict__ statsOut,
    unsigned short (*Ks)[64 * 64], unsigned short (*Vs)[64 * 64]) {
  const int l31 = lane & 31, l32 = lane >> 5;
  const int sw = l31 & 7;

  const unsigned short* qptr =
      Qb + (size_t)(b * 2048 + qt * 128 + w * 32 + l31) * 1024 + h * 64 + l32 * 8;
  bf16x8 qa[4];
#pragma unroll
  for (int kk = 0; kk < 4; ++kk) qa[kk] = *(const bf16x8*)(qptr + kk * 16);

  f32x16 oacc[2] = {};
  float m = -3e38f, l = 0.f;

  stage_tiles(Kgb, Vgb, Ks[0], Vs[0], t0 * 64, w, lane);
  stage_tiles(Kgb, Vgb, Ks[1], Vs[1], (t0 + 1) * 64, w, lane);

  int ib = 0, is_ = 2;
  for (int t = t0; t < t1; ++t) {
    if (t < t1 - 1) {
      asm volatile("s_waitcnt vmcnt(4)" ::: "memory");
    } else {
      asm volatile("s_waitcnt vmcnt(0)" ::: "memory");
    }
    __builtin_amdgcn_s_barrier();
    __builtin_amdgcn_sched_barrier(0);
    if (t + 2 < t1)
      stage_tiles(Kgb, Vgb, Ks[is_], Vs[is_], (t + 2) * 64, w, lane);

    // QK^T swapped: St = mfma32(K_frag, Q_frag) -> S^T[kv][q], q = l31
    const char* ksb = (const char*)Ks[ib];
    f32x16 st[2];
    __builtin_amdgcn_s_setprio(1);
#pragma unroll
    for (int f = 0; f < 2; ++f) {
      const char* kb = ksb + (f * 32 + l31) * 128;
      f32x16 z = {};
#pragma unroll
      for (int kk = 0; kk < 4; ++kk) {
        bf16x8 kf = *(const bf16x8*)(kb + ((((kk << 1) | l32) ^ sw) * 16));
        z = MFMA32(kf, qa[kk], z);
      }
      st[f] = z;
    }
    __builtin_amdgcn_s_setprio(0);

    // causal mask (diagonal tiles only; prefix streams never trigger this)
    if (t >= 2 * qt + (w >> 1)) {
      const int qg = qt * 128 + w * 32 + l31;
      const int kvb = t * 64 + 4 * l32;
#pragma unroll
      for (int f = 0; f < 2; ++f)
#pragma unroll
        for (int reg = 0; reg < 16; ++reg) {
          int kv = kvb + 32 * f + (reg & 3) + 8 * (reg >> 2);
          if (kv > qg) st[f][reg] = -3e38f;
        }
    }

    // row max: in-register tree + 1 swap across lane halves
    float a8[8];
#pragma unroll
    for (int j = 0; j < 8; ++j)
      a8[j] = fmaxf(fmaxf(st[0][j], st[0][j + 8]), fmaxf(st[1][j], st[1][j + 8]));
    float pm = fmaxf(fmaxf(fmaxf(a8[0], a8[1]), fmaxf(a8[2], a8[3])),
                     fmaxf(fmaxf(a8[4], a8[5]), fmaxf(a8[6], a8[7])));
    pm = fmaxf(pm, __shfl_xor(pm, 32, 64));

    // defer-max: rescale only when running max grew by > 8 (log2 domain)
    if (!__all(pm - m <= 8.0f)) {
      float mn = fmaxf(m, pm);
      float al = fexp2(m - mn);
      l *= al;
#pragma unroll
      for (int df = 0; df < 2; ++df)
#pragma unroll
        for (int reg = 0; reg < 16; ++reg) oacc[df][reg] *= al;
      m = mn;
    }

    // p = exp2(s - m), pack to bf16 pairs
    unsigned pku[2][4][2];
    float rs0 = 0.f, rs1 = 0.f;
#pragma unroll
    for (int f = 0; f < 2; ++f)
#pragma unroll
      for (int rr = 0; rr < 4; ++rr)
#pragma unroll
        for (int i = 0; i < 2; ++i) {
          float p0 = fexp2(st[f][4 * rr + 2 * i] - m);
          float p1 = fexp2(st[f][4 * rr + 2 * i + 1] - m);
          rs0 += p0; rs1 += p1;
          pku[f][rr][i] = cvtpk(p0, p1);
        }
    float rs = rs0 + rs1;
    rs += __shfl_xor(rs, 32, 64);
    l += rs;

    // redistribute P^T into B-operand frags via permlane32_swap
    union FB { unsigned u[4]; bf16x8 v; };
    FB pfrag[4];
#pragma unroll
    for (int kk = 0; kk < 4; ++kk) {
      const int f = kk >> 1, kl = kk & 1;
      unsigned o00, o10, o01, o11;
      plswap(pku[f][2 * kl][0], pku[f][2 * kl + 1][0], o00, o10);
      plswap(pku[f][2 * kl][1], pku[f][2 * kl + 1][1], o01, o11);
      pfrag[kk].u[0] = o00; pfrag[kk].u[1] = o01;
      pfrag[kk].u[2] = o10; pfrag[kk].u[3] = o11;
    }

    // PV swapped: O^T[d][q] += mfma32(V^T_frag, P^T_frag)
    const char* vsb = (const char*)Vs[ib];
    __builtin_amdgcn_s_setprio(1);
#pragma unroll
    for (int df = 0; df < 2; ++df) {
      const char* vb = vsb + (df * 32 + l31) * 128;
#pragma unroll
      for (int kk = 0; kk < 4; ++kk) {
        bf16x8 vf = *(const bf16x8*)(vb + ((((kk << 1) | l32) ^ sw) * 16));
        oacc[df] = MFMA32(vf, pfrag[kk].v, oacc[df]);
      }
    }
    __builtin_amdgcn_s_setprio(0);

    ib = (ib == 2) ? 0 : ib + 1;
    is_ = (is_ == 2) ? 0 : is_ + 1;
  }

  // output: normalized (final) or raw partial (unnormalized) + stats
  const float sc = finalize ? (1.0f / l) : 1.0f;
  unsigned short* ob = outBase + (size_t)(w * 32 + l31) * ostride + 4 * l32;
#pragma unroll
  for (int df = 0; df < 2; ++df)
#pragma unroll
    for (int rr = 0; rr < 4; ++rr)
#pragma unroll
      for (int i = 0; i < 2; ++i) {
        *(unsigned*)(ob + df * 32 + rr * 8 + 2 * i) =
            pk2b(oacc[df][4 * rr + 2 * i] * sc, oacc[df][4 * rr + 2 * i + 1] * sc);
      }
  if (!finalize && l32 == 0) {
    float2 st2 = {m, l};
    *(float2*)(statsOut + (w * 32 + l31) * 2) = st2;
  }
}

__global__ __launch_bounds__(256, 2) void attn_kernel(
    const unsigned short* __restrict__ Qb,
    const unsigned short* __restrict__ Kb,
    const unsigned short* __restrict__ VbT,   // [32][64][2048]
    unsigned short* __restrict__ Ob,
    unsigned short* __restrict__ P2,          // [256][128][64] partial2
    float* __restrict__ stats1, float* __restrict__ stats2) {
  __shared__ unsigned short Ks[3][64 * 64];
  __shared__ unsigned short Vs[3][64 * 64];
  const int bh = blockIdx.x;                  // fastest -> same bh lands on one XCD
  const int y = blockIdx.y;                   // 0..15
  const int j = y >> 1, half = y & 1;
  const int b = bh >> 4, h = bh & 15;
  const int qtB = 15 - j;
  const int x = 15 - 2 * j;                   // split point of big chunk
  const int cid = bh * 8 + j;
  const int tid = threadIdx.x, w = tid >> 6, lane = tid & 63;

  const unsigned short* Kgb = Kb + (size_t)b * 2048 * 1024 + h * 64;
  const unsigned short* Vgb = VbT + (size_t)bh * 131072;

  if (half == 0) {
    // prefix of big chunk -> unnormalized partial1 into Ob slot + stats1
    attn_stream(qtB, 0, x, false, b, h, w, lane, Qb, Kgb, Vgb,
                Ob + (size_t)(b * 2048 + qtB * 128) * 1024 + h * 64, 1024,
                stats1 + cid * 256, Ks, Vs);
    __syncthreads();
    // whole small chunk -> final
    attn_stream(j, 0, 2 * j + 2, true, b, h, w, lane, Qb, Kgb, Vgb,
                Ob + (size_t)(b * 2048 + j * 128) * 1024 + h * 64, 1024,
                nullptr, Ks, Vs);
  } else {
    // remainder of big chunk -> unnormalized partial2 into P2 + stats2
    attn_stream(qtB, x, 32 - 2 * j, false, b, h, w, lane, Qb, Kgb, Vgb,
                P2 + (size_t)cid * 8192, 64,
                stats2 + cid * 256, Ks, Vs);
  }
}

// ---------------- merge: LSE-combine split big chunks ----------------

__global__ __launch_bounds__(256) void merge_kernel(
    unsigned short* __restrict__ Ob, const unsigned short* __restrict__ P2,
    const float* __restrict__ stats1, const float* __restrict__ stats2) {
  const int cid = blockIdx.x;                 // 256
  const int bh = cid >> 3, j = cid & 7, qt = 15 - j;
  const int b = bh >> 4, h = bh & 15;
  const int tid = threadIdx.x;
  const int r = tid >> 1, ch = (tid & 1) * 32;

  const float m1 = stats1[cid * 256 + r * 2], l1 = stats1[cid * 256 + r * 2 + 1];
  const float m2 = stats2[cid * 256 + r * 2], l2 = stats2[cid * 256 + r * 2 + 1];
  const float M = fmaxf(m1, m2);
  const float a1 = fexp2(m1 - M), a2 = fexp2(m2 - M);
  const float invL = 1.0f / (l1 * a1 + l2 * a2);
  const float c1 = a1 * invL, c2 = a2 * invL;

  unsigned short* o1 = Ob + (size_t)(b * 2048 + qt * 128 + r) * 1024 + h * 64 + ch;
  const unsigned short* o2 = P2 + (size_t)cid * 8192 + r * 64 + ch;
#pragma unroll
  for (int i = 0; i < 32; i += 8) {
    int4v v1 = *(const int4v*)(o1 + i);
    int4v v2 = *(const int4v*)(o2 + i);
    int4v ro;
#pragma unroll
    for (int k = 0; k < 4; ++k) {
      unsigned u1 = (unsigned)v1[k], u2 = (unsigned)v2[k];
      float lo = b2f((unsigned short)u1) * c1 + b2f((unsigned short)u2) * c2;
      float hi = b2f((unsigned short)(u1 >> 16)) * c1 + b2f((unsigned short)(u2 >> 16)) * c2;
      ro[k] = (int)pk2b(lo, hi);
    }
    *(int4v*)(o1 + i) = ro;
  }
}

// ---------------- launch ----------------

extern "C" void kernel_launch(void* const* d_in, const int* in_sizes, int n_in,
                              void* d_out, int out_size, void* d_ws, size_t ws_size,
                              hipStream_t stream) {
  (void)in_sizes; (void)n_in; (void)out_size; (void)ws_size;
  const float* x  = (const float*)d_in[0];
  const int*  tp  = (const int*)d_in[1];
  const float* Wq = (const float*)d_in[2];
  const float* Wk = (const float*)d_in[3];
  const float* Wv = (const float*)d_in[4];
  const float* Wo = (const float*)d_in[5];
  float* out = (float*)d_out;

  char* ws = (char*)d_ws;
  unsigned short* xb    = (unsigned short*)(ws);                       // 8MB
  unsigned short* Ob    = (unsigned short*)(ws);                       // reuses xb
  unsigned short* Wqkvb = (unsigned short*)(ws + (8ull << 20));        // 6MB
  unsigned short* P2    = (unsigned short*)(ws + (8ull << 20));        // reuses Wqkvb (4MB)
  unsigned short* Wob   = (unsigned short*)(ws + (14ull << 20));       // 2MB
  unsigned short* Qb    = (unsigned short*)(ws + (16ull << 20));       // 8MB
  unsigned short* Kb    = (unsigned short*)(ws + (24ull << 20));       // 8MB
  unsigned short* VbT   = (unsigned short*)(ws + (32ull << 20));       // 8MB
  float* cosT   = (float*)(ws + (40ull << 20));                        // 256KB
  float* sinT   = (float*)(ws + (40ull << 20) + 262144);               // 256KB
  float* stats1 = (float*)(ws + (40ull << 20));                        // reuses cosT
  float* stats2 = (float*)(ws + (40ull << 20) + 262144);               // reuses sinT

  prep_kernel<<<8256, 256, 0, stream>>>(x, Wq, Wk, Wv, Wo, tp, xb, Wqkvb, Wob, cosT, sinT);
  gemm_qkv_kernel<<<768, 256, 0, stream>>>(xb, Wqkvb, Qb, Kb, VbT, cosT, sinT);
  attn_kernel<<<dim3(32, 16), 256, 0, stream>>>(Qb, Kb, VbT, Ob, P2, stats1, stats2);
  merge_kernel<<<256, 256, 0, stream>>>(Ob, P2, stats1, stats2);
  gemm_out_kernel<<<256, 256, 0, stream>>>(Ob, Wob, out);
}

// Round 15
// 105.930 us; speedup vs baseline: 1.1780x; 1.0703x over previous
//
#include <hip/hip_runtime.h>
#include <hip/hip_bf16.h>

// MHA forward: b=2, s=2048, d=1024, h=16, dk=64. fp32 in/out, bf16 MFMA internally.
// ws layout (40.5 MB):
//   0      : xb [4096][1024] bf16 (8MB)  -- dead after gemm_qkv, reused as Ob (attn out)
//   8 MB   : Wqkvb [3072][1024] bf16 (6MB) -- dead after gemm_qkv, reused as P2 (4MB)
//   14 MB  : Wob [1024][1024] bf16 (2MB)
//   16 MB  : Qb [4096][1024] bf16 (8MB)  (RoPE'd, log2-domain scale)
//   24 MB  : Kb [4096][1024] bf16 (8MB)  (RoPE'd)
//   32 MB  : VbT [32 bh][64 dk][2048 seq] bf16 (8MB)
//   40 MB  : cosT/sinT (512KB) -- dead after gemm_qkv, reused as stats1/stats2

typedef __attribute__((ext_vector_type(8))) __bf16 bf16x8;
typedef __attribute__((ext_vector_type(4))) float f32x4;
typedef __attribute__((ext_vector_type(16))) float f32x16;
typedef __attribute__((ext_vector_type(4))) int int4v;
typedef __attribute__((ext_vector_type(2))) unsigned int uint2v;

#define MFMA16(a, b, c) __builtin_amdgcn_mfma_f32_16x16x32_bf16(a, b, c, 0, 0, 0)
#define MFMA32(a, b, c) __builtin_amdgcn_mfma_f32_32x32x16_bf16(a, b, c, 0, 0, 0)

__device__ inline unsigned short f2b(float f) {
  unsigned u = __builtin_bit_cast(unsigned, f);
  u = (u + 0x7FFF + ((u >> 16) & 1)) >> 16;   // RNE, finite inputs only
  return (unsigned short)u;
}

__device__ inline float b2f(unsigned short u) {
  return __builtin_bit_cast(float, ((unsigned)u) << 16);
}

__device__ inline unsigned pk2b(float lo, float hi) {
  return (unsigned)f2b(lo) | ((unsigned)f2b(hi) << 16);
}

__device__ inline unsigned cvtpk(float lo, float hi) {
  unsigned r;
  asm("v_cvt_pk_bf16_f32 %0, %1, %2" : "=v"(r) : "v"(lo), "v"(hi));
  return r;
}

__device__ inline void plswap(unsigned a, unsigned b, unsigned& o0, unsigned& o1) {
#if __has_builtin(__builtin_amdgcn_permlane32_swap)
  auto r = __builtin_amdgcn_permlane32_swap(a, b, false, false);
  o0 = r[0];
  o1 = r[1];
#else
  unsigned sa = (unsigned)__shfl_xor((int)a, 32, 64);
  unsigned sb = (unsigned)__shfl_xor((int)b, 32, 64);
  bool hi = (threadIdx.x & 32) != 0;
  o0 = hi ? sb : a;
  o1 = hi ? b : sa;
#endif
}

__device__ inline float fexp2(float x) {
#if __has_builtin(__builtin_amdgcn_exp2f)
  return __builtin_amdgcn_exp2f(x);
#else
  return exp2f(x);
#endif
}

// ---------------- fused prep ----------------

__device__ inline void cvt4(const float* __restrict__ s, unsigned short* __restrict__ d,
                            int i, float sc) {
  float4 v = *(const float4*)(s + i);
  uint2v p = {pk2b(v.x * sc, v.y * sc), pk2b(v.z * sc, v.w * sc)};
  *(uint2v*)(d + i) = p;
}

__global__ __launch_bounds__(256) void prep_kernel(
    const float* __restrict__ x, const float* __restrict__ Wq,
    const float* __restrict__ Wk, const float* __restrict__ Wv,
    const float* __restrict__ Wo, const int* __restrict__ tp,
    unsigned short* __restrict__ xb, unsigned short* __restrict__ Wqkvb,
    unsigned short* __restrict__ Wob, float* __restrict__ cosT,
    float* __restrict__ sinT) {
  int t = blockIdx.x * 256 + threadIdx.x;
  if (t < 1048576) {
    cvt4(x, xb, t * 4, 1.0f);
  } else if (t < 1310720) {
    cvt4(Wq, Wqkvb, (t - 1048576) * 4, 0.18033688f);   // (1/8)*log2(e)
  } else if (t < 1572864) {
    cvt4(Wk, Wqkvb + 1048576, (t - 1310720) * 4, 1.0f);
  } else if (t < 1835008) {
    cvt4(Wv, Wqkvb + 2097152, (t - 1572864) * 4, 1.0f);
  } else if (t < 2097152) {
    cvt4(Wo, Wob, (t - 1835008) * 4, 1.0f);
  } else {
    int base = (t - 2097152) * 4;
#pragma unroll
    for (int j = 0; j < 4; ++j) {
      int idx = base + j;
      int p = idx >> 5, i = idx & 31;
      float pos = (float)tp[p];
      float freq = powf(10000.0f, -(float)i / 32.0f);
      float ang = pos * freq;
      cosT[idx] = cosf(ang);
      sinT[idx] = sinf(ang);
    }
  }
}

// ---------------- GEMM 1 staging: 256x64 A + 192x64 B, xor-swizzled, B 32-group-permuted --

__device__ __forceinline__ void g_stage_qkv(const unsigned short* __restrict__ A,
                                            const unsigned short* __restrict__ B,
                                            unsigned short* __restrict__ As,
                                            unsigned short* __restrict__ Bs,
                                            int m0, int n0, int k0, int w, int lane) {
  const int srow = lane >> 3;
  const int schunk = (lane & 7) ^ srow;          // inverse swizzle on global source
#pragma unroll
  for (int c = 0; c < 4; ++c) {                  // A: 8 waves x 32 rows
    const int rb = w * 32 + c * 8;
    const unsigned short* ga = A + (size_t)(m0 + rb + srow) * 1024 + k0 + schunk * 8;
    __builtin_amdgcn_global_load_lds(
        (const __attribute__((address_space(1))) void*)ga,
        (__attribute__((address_space(3))) void*)(As + rb * 64), 16, 0, 0);
  }
#pragma unroll
  for (int c = 0; c < 3; ++c) {                  // B: 8 waves x 24 rows
    const int rb = w * 24 + c * 8;
    const int rl = rb + srow;
    const int rB = n0 + (rl & 224) + ((rl & 15) << 1) + ((rl >> 4) & 1);  // perm per 32-group
    const unsigned short* gb = B + (size_t)rB * 1024 + k0 + schunk * 8;
    __builtin_amdgcn_global_load_lds(
        (const __attribute__((address_space(1))) void*)gb,
        (__attribute__((address_space(3))) void*)(Bs + rb * 64), 16, 0, 0);
  }
}

// ---------------- GEMM 1: QKV projection + RoPE epilogue ----------------
// 256x192 tile, 8 waves (4M x 2N, per-wave 64x96), BK=64, 2-buf counted vmcnt(7).
// Grid = 16x16 = 256 blocks = exactly 1 round (zero tail). LDS 112KB, 2 waves/SIMD.

__global__ __launch_bounds__(512, 2) void gemm_qkv_kernel(
    const unsigned short* __restrict__ A,    // xb
    const unsigned short* __restrict__ B,    // Wqkvb
    unsigned short* __restrict__ Qb, unsigned short* __restrict__ Kb,
    unsigned short* __restrict__ VbT,        // [32][64][2048]
    const float* __restrict__ cosT, const float* __restrict__ sinT) {
  __shared__ unsigned short As[2][256 * 64];  // 64KB
  __shared__ unsigned short Bs[2][192 * 64];  // 48KB
  // XCD slab remap: 8 XCDs = 4x2 slabs of 4m x 8n tiles
  const int bid = blockIdx.x;
  const int xcd = bid & 7, q = bid >> 3;         // q in [0,32)
  const int mg = xcd >> 1, ng = xcd & 1;
  const int m0 = (mg * 4 + (q & 3)) * 256;
  const int n0 = (ng * 8 + (q >> 2)) * 192;
  const int tid = threadIdx.x, w = tid >> 6, lane = tid & 63;
  const int l15 = lane & 15, l4 = lane >> 4;
  const int wr = w & 3, wc = w >> 2;             // 4M x 2N

  f32x4 acc[4][6] = {};

  g_stage_qkv(A, B, As[0], Bs[0], m0, n0, 0, w, lane);   // 7 loads in flight

  int cur = 0;
  for (int k0 = 0; k0 < 1024; k0 += 64) {
    __builtin_amdgcn_s_barrier();                        // readers of buf[cur^1] done
    if (k0 + 64 < 1024) {
      g_stage_qkv(A, B, As[cur ^ 1], Bs[cur ^ 1], m0, n0, k0 + 64, w, lane);
      asm volatile("s_waitcnt vmcnt(7)" ::: "memory");   // stage(k) landed; stage(k+1) flies
    } else {
      asm volatile("s_waitcnt vmcnt(0)" ::: "memory");
    }
    __builtin_amdgcn_sched_barrier(0);

    const unsigned short* as = As[cur];
    const unsigned short* bs = Bs[cur];
#pragma unroll
    for (int kk = 0; kk < 2; ++kk) {
      bf16x8 af[4], bfr[6];
#pragma unroll
      for (int m = 0; m < 4; m++) {
        const int row = wr * 64 + m * 16 + l15;
        af[m] = *(const bf16x8*)(&as[row * 64 + (((kk * 4 + l4) ^ (l15 & 7)) * 8)]);
      }
#pragma unroll
      for (int n = 0; n < 6; n++) {
        const int row = wc * 96 + n * 16 + l15;
        bfr[n] = *(const bf16x8*)(&bs[row * 64 + (((kk * 4 + l4) ^ (l15 & 7)) * 8)]);
      }
#pragma unroll
      for (int m = 0; m < 4; m++)
#pragma unroll
        for (int n = 0; n < 6; n++)
          acc[m][n] = MFMA16(af[m], bfr[n], acc[m][n]);
    }
    cur ^= 1;
  }

  // epilogue: frag-pair (2k,2k+1) = output cols (g, g+1), g = n0 + wc*96 + k*32 + 2*l15.
  // Each 32-col pair lies in exactly one region (Q / K / V).
#pragma unroll
  for (int k = 0; k < 3; k++) {
    const int gcol = n0 + wc * 96 + k * 32 + 2 * l15;
    const int region = gcol >> 10;
    if (region < 2) {
      unsigned short* dst = (region == 0) ? Qb : Kb;
      const int col = gcol & 1023;
      const int pi = (gcol & 63) >> 1;
#pragma unroll
      for (int m = 0; m < 4; m++) {
        const int row0 = m0 + wr * 64 + m * 16 + l4 * 4;
#pragma unroll
        for (int r = 0; r < 4; r++) {
          const int pos = (row0 + r) & 2047;
          float c = cosT[pos * 32 + pi], s = sinT[pos * 32 + pi];
          float v0 = acc[m][2 * k][r], v1 = acc[m][2 * k + 1][r];
          float r1 = fmaf(v0, c, -v1 * s);
          float r2 = fmaf(v1, c, v0 * s);
          *(unsigned*)(dst + (size_t)(row0 + r) * 1024 + col) = pk2b(r1, r2);
        }
      }
    } else {
      const int dkg = gcol - 2048;
      const int h = dkg >> 6, dk = dkg & 63;
#pragma unroll
      for (int m = 0; m < 4; m++) {
        const int row0 = m0 + wr * 64 + m * 16 + l4 * 4;
        const int bb = row0 >> 11, seq = row0 & 2047;
        unsigned short* vp = VbT + (size_t)(bb * 16 + h) * 131072 + dk * 2048 + seq;
        uint2v e = {pk2b(acc[m][2 * k][0], acc[m][2 * k][1]),
                    pk2b(acc[m][2 * k][2], acc[m][2 * k][3])};
        *(uint2v*)vp = e;
        uint2v o = {pk2b(acc[m][2 * k + 1][0], acc[m][2 * k + 1][1]),
                    pk2b(acc[m][2 * k + 1][2], acc[m][2 * k + 1][3])};
        *(uint2v*)(vp + 2048) = o;
      }
    }
  }
}

// ---------------- GEMM 2 staging (BK=64, xor-swizzled, B rows bit-permuted) -------------

__device__ __forceinline__ void g_stage(const unsigned short* __restrict__ A,
                                        const unsigned short* __restrict__ B,
                                        unsigned short* __restrict__ As,
                                        unsigned short* __restrict__ Bs,
                                        int m0, int n0, int k0, int w, int lane) {
  const int srow = lane >> 3;
  const int schunk = (lane & 7) ^ srow;          // inverse swizzle on global source
#pragma unroll
  for (int c = 0; c < 4; ++c) {
    const int rb = w * 32 + c * 8;
    const unsigned short* ga = A + (size_t)(m0 + rb + srow) * 1024 + k0 + schunk * 8;
    __builtin_amdgcn_global_load_lds(
        (const __attribute__((address_space(1))) void*)ga,
        (__attribute__((address_space(3))) void*)(As + rb * 64), 16, 0, 0);
    const int rl = rb + srow;
    const int rB = n0 + (rl & 96) + ((rl & 15) << 1) + ((rl >> 4) & 1);
    const unsigned short* gb = B + (size_t)rB * 1024 + k0 + schunk * 8;
    __builtin_amdgcn_global_load_lds(
        (const __attribute__((address_space(1))) void*)gb,
        (__attribute__((address_space(3))) void*)(Bs + rb * 64), 16, 0, 0);
  }
}

// ---------------- GEMM 2: output projection, counted-vmcnt 2-buf pipeline ---------------

__global__ __launch_bounds__(256) void gemm_out_kernel(
    const unsigned short* __restrict__ A,    // Ob [4096][1024]
    const unsigned short* __restrict__ B,    // Wob [1024][1024]
    float* __restrict__ out) {
  __shared__ unsigned short As[2][128 * 64];
  __shared__ unsigned short Bs[2][128 * 64];
  const int bid = blockIdx.x;
  const int sw = (bid & 7) * 32 + (bid >> 3);
  const int n0 = (sw % 8) * 128, m0 = (sw / 8) * 128;
  const int tid = threadIdx.x, w = tid >> 6, lane = tid & 63;
  const int l15 = lane & 15, l4 = lane >> 4;
  const int wr = w >> 1, wc = w & 1;

  f32x4 acc[4][4] = {};

  g_stage(A, B, As[0], Bs[0], m0, n0, 0, w, lane);

  int cur = 0;
  for (int k0 = 0; k0 < 1024; k0 += 64) {
    __builtin_amdgcn_s_barrier();
    if (k0 + 64 < 1024) {
      g_stage(A, B, As[cur ^ 1], Bs[cur ^ 1], m0, n0, k0 + 64, w, lane);
      asm volatile("s_waitcnt vmcnt(8)" ::: "memory");
    } else {
      asm volatile("s_waitcnt vmcnt(0)" ::: "memory");
    }
    __builtin_amdgcn_sched_barrier(0);

    const unsigned short* as = As[cur];
    const unsigned short* bs = Bs[cur];
#pragma unroll
    for (int kk = 0; kk < 2; ++kk) {
      bf16x8 af[4], bfr[4];
#pragma unroll
      for (int m = 0; m < 4; m++) {
        const int row = wr * 64 + m * 16 + l15;
        af[m] = *(const bf16x8*)(&as[row * 64 + (((kk * 4 + l4) ^ (l15 & 7)) * 8)]);
      }
#pragma unroll
      for (int n = 0; n < 4; n++) {
        const int row = wc * 64 + n * 16 + l15;
        bfr[n] = *(const bf16x8*)(&bs[row * 64 + (((kk * 4 + l4) ^ (l15 & 7)) * 8)]);
      }
#pragma unroll
      for (int m = 0; m < 4; m++)
#pragma unroll
        for (int n = 0; n < 4; n++)
          acc[m][n] = MFMA16(af[m], bfr[n], acc[m][n]);
    }
    cur ^= 1;
  }

#pragma unroll
  for (int m = 0; m < 4; m++) {
    const int row0 = m0 + wr * 64 + m * 16 + l4 * 4;
#pragma unroll
    for (int k = 0; k < 2; k++) {
      const int col = n0 + wc * 64 + k * 32 + 2 * l15;
#pragma unroll
      for (int r = 0; r < 4; r++) {
        float2 v = {acc[m][2 * k][r], acc[m][2 * k + 1][r]};
        *(float2*)(out + (size_t)(row0 + r) * 1024 + col) = v;
      }
    }
  }
}

// ---------------- Flash attention: 512 equal 17-tile blocks + LSE merge ----------------

__device__ __forceinline__ void stage_tiles(const unsigned short* __restrict__ Kgb,
                                            const unsigned short* __restrict__ Vgb,
                                            unsigned short* KsBuf, unsigned short* VsBuf,
                                            int kv0, int w, int lane) {
#pragma unroll
  for (int c = 0; c < 2; ++c) {
    const int rowbase = w * 16 + c * 8;
    const int row = rowbase + (lane >> 3);
    const int chunk = (lane & 7) ^ (lane >> 3);    // inverse swizzle on global source
    const unsigned short* gk = Kgb + (size_t)(kv0 + row) * 1024 + chunk * 8;
    __builtin_amdgcn_global_load_lds(
        (const __attribute__((address_space(1))) void*)gk,
        (__attribute__((address_space(3))) void*)(KsBuf + rowbase * 64), 16, 0, 0);
    const unsigned short* gv = Vgb + (size_t)row * 2048 + kv0 + chunk * 8;
    __builtin_amdgcn_global_load_lds(
        (const __attribute__((address_space(1))) void*)gv,
        (__attribute__((address_space(3))) void*)(VsBuf + rowbase * 64), 16, 0, 0);
  }
}

__device__ __forceinline__ void attn_stream(
    int qt, int t0, int t1, bool finalize,
    int b, int h, int w, int lane,
    const unsigned short* __restrict__ Qb,
    const unsigned short* __restrict__ Kgb,
    const unsigned short* __restrict__ Vgb,
    unsigned short* __restrict__ outBase, int ostride,
    float* __restrict__ statsOut,
    unsigned short (*Ks)[64 * 64], unsigned short (*Vs)[64 * 64]) {
  const int l31 = lane & 31, l32 = lane >> 5;
  const int sw = l31 & 7;

  const unsigned short* qptr =
      Qb + (size_t)(b * 2048 + qt * 128 + w * 32 + l31) * 1024 + h * 64 + l32 * 8;
  bf16x8 qa[4];
#pragma unroll
  for (int kk = 0; kk < 4; ++kk) qa[kk] = *(const bf16x8*)(qptr + kk * 16);

  f32x16 oacc[2] = {};
  float m = -3e38f, l = 0.f;

  stage_tiles(Kgb, Vgb, Ks[0], Vs[0], t0 * 64, w, lane);
  stage_tiles(Kgb, Vgb, Ks[1], Vs[1], (t0 + 1) * 64, w, lane);

  int ib = 0, is_ = 2;
  for (int t = t0; t < t1; ++t) {
    if (t < t1 - 1) {
      asm volatile("s_waitcnt vmcnt(4)" ::: "memory");
    } else {
      asm volatile("s_waitcnt vmcnt(0)" ::: "memory");
    }
    __builtin_amdgcn_s_barrier();
    __builtin_amdgcn_sched_barrier(0);
    if (t + 2 < t1)
      stage_tiles(Kgb, Vgb, Ks[is_], Vs[is_], (t + 2) * 64, w, lane);

    // QK^T swapped: St = mfma32(K_frag, Q_frag) -> S^T[kv][q], q = l31
    const char* ksb = (const char*)Ks[ib];
    f32x16 st[2];
    __builtin_amdgcn_s_setprio(1);
#pragma unroll
    for (int f = 0; f < 2; ++f) {
      const char* kb = ksb + (f * 32 + l31) * 128;
      f32x16 z = {};
#pragma unroll
      for (int kk = 0; kk < 4; ++kk) {
        bf16x8 kf = *(const bf16x8*)(kb + ((((kk << 1) | l32) ^ sw) * 16));
        z = MFMA32(kf, qa[kk], z);
      }
      st[f] = z;
    }
    __builtin_amdgcn_s_setprio(0);

    // causal mask (diagonal tiles only; prefix streams never trigger this)
    if (t >= 2 * qt + (w >> 1)) {
      const int qg = qt * 128 + w * 32 + l31;
      const int kvb = t * 64 + 4 * l32;
#pragma unroll
      for (int f = 0; f < 2; ++f)
#pragma unroll
        for (int reg = 0; reg < 16; ++reg) {
          int kv = kvb + 32 * f + (reg & 3) + 8 * (reg >> 2);
          if (kv > qg) st[f][reg] = -3e38f;
        }
    }

    // row max: in-register tree + 1 swap across lane halves
    float a8[8];
#pragma unroll
    for (int j = 0; j < 8; ++j)
      a8[j] = fmaxf(fmaxf(st[0][j], st[0][j + 8]), fmaxf(st[1][j], st[1][j + 8]));
    float pm = fmaxf(fmaxf(fmaxf(a8[0], a8[1]), fmaxf(a8[2], a8[3])),
                     fmaxf(fmaxf(a8[4], a8[5]), fmaxf(a8[6], a8[7])));
    pm = fmaxf(pm, __shfl_xor(pm, 32, 64));

    // defer-max: rescale only when running max grew by > 8 (log2 domain)
    if (!__all(pm - m <= 8.0f)) {
      float mn = fmaxf(m, pm);
      float al = fexp2(m - mn);
      l *= al;
#pragma unroll
      for (int df = 0; df < 2; ++df)
#pragma unroll
        for (int reg = 0; reg < 16; ++reg) oacc[df][reg] *= al;
      m = mn;
    }

    // p = exp2(s - m), pack to bf16 pairs
    unsigned pku[2][4][2];
    float rs0 = 0.f, rs1 = 0.f;
#pragma unroll
    for (int f = 0; f < 2; ++f)
#pragma unroll
      for (int rr = 0; rr < 4; ++rr)
#pragma unroll
        for (int i = 0; i < 2; ++i) {
          float p0 = fexp2(st[f][4 * rr + 2 * i] - m);
          float p1 = fexp2(st[f][4 * rr + 2 * i + 1] - m);
          rs0 += p0; rs1 += p1;
          pku[f][rr][i] = cvtpk(p0, p1);
        }
    float rs = rs0 + rs1;
    rs += __shfl_xor(rs, 32, 64);
    l += rs;

    // redistribute P^T into B-operand frags via permlane32_swap
    union FB { unsigned u[4]; bf16x8 v; };
    FB pfrag[4];
#pragma unroll
    for (int kk = 0; kk < 4; ++kk) {
      const int f = kk >> 1, kl = kk & 1;
      unsigned o00, o10, o01, o11;
      plswap(pku[f][2 * kl][0], pku[f][2 * kl + 1][0], o00, o10);
      plswap(pku[f][2 * kl][1], pku[f][2 * kl + 1][1], o01, o11);
      pfrag[kk].u[0] = o00; pfrag[kk].u[1] = o01;
      pfrag[kk].u[2] = o10; pfrag[kk].u[3] = o11;
    }

    // PV swapped: O^T[d][q] += mfma32(V^T_frag, P^T_frag)
    const char* vsb = (const char*)Vs[ib];
    __builtin_amdgcn_s_setprio(1);
#pragma unroll
    for (int df = 0; df < 2; ++df) {
      const char* vb = vsb + (df * 32 + l31) * 128;
#pragma unroll
      for (int kk = 0; kk < 4; ++kk) {
        bf16x8 vf = *(const bf16x8*)(vb + ((((kk << 1) | l32) ^ sw) * 16));
        oacc[df] = MFMA32(vf, pfrag[kk].v, oacc[df]);
      }
    }
    __builtin_amdgcn_s_setprio(0);

    ib = (ib == 2) ? 0 : ib + 1;
    is_ = (is_ == 2) ? 0 : is_ + 1;
  }

  // output: normalized (final) or raw partial (unnormalized) + stats
  const float sc = finalize ? (1.0f / l) : 1.0f;
  unsigned short* ob = outBase + (size_t)(w * 32 + l31) * ostride + 4 * l32;
#pragma unroll
  for (int df = 0; df < 2; ++df)
#pragma unroll
    for (int rr = 0; rr < 4; ++rr)
#pragma unroll
      for (int i = 0; i < 2; ++i) {
        *(unsigned*)(ob + df * 32 + rr * 8 + 2 * i) =
            pk2b(oacc[df][4 * rr + 2 * i] * sc, oacc[df][4 * rr + 2 * i + 1] * sc);
      }
  if (!finalize && l32 == 0) {
    float2 st2 = {m, l};
    *(float2*)(statsOut + (w * 32 + l31) * 2) = st2;
  }
}

__global__ __launch_bounds__(256, 2) void attn_kernel(
    const unsigned short* __restrict__ Qb,
    const unsigned short* __restrict__ Kb,
    const unsigned short* __restrict__ VbT,   // [32][64][2048]
    unsigned short* __restrict__ Ob,
    unsigned short* __restrict__ P2,          // [256][128][64] partial2
    float* __restrict__ stats1, float* __restrict__ stats2) {
  __shared__ unsigned short Ks[3][64 * 64];
  __shared__ unsigned short Vs[3][64 * 64];
  const int bh = blockIdx.x;                  // fastest -> same bh lands on one XCD
  const int y = blockIdx.y;                   // 0..15
  const int j = y >> 1, half = y & 1;
  const int b = bh >> 4, h = bh & 15;
  const int qtB = 15 - j;
  const int x = 15 - 2 * j;                   // split point of big chunk
  const int cid = bh * 8 + j;
  const int tid = threadIdx.x, w = tid >> 6, lane = tid & 63;

  const unsigned short* Kgb = Kb + (size_t)b * 2048 * 1024 + h * 64;
  const unsigned short* Vgb = VbT + (size_t)bh * 131072;

  if (half == 0) {
    // prefix of big chunk -> unnormalized partial1 into Ob slot + stats1
    attn_stream(qtB, 0, x, false, b, h, w, lane, Qb, Kgb, Vgb,
                Ob + (size_t)(b * 2048 + qtB * 128) * 1024 + h * 64, 1024,
                stats1 + cid * 256, Ks, Vs);
    __syncthreads();
    // whole small chunk -> final
    attn_stream(j, 0, 2 * j + 2, true, b, h, w, lane, Qb, Kgb, Vgb,
                Ob + (size_t)(b * 2048 + j * 128) * 1024 + h * 64, 1024,
                nullptr, Ks, Vs);
  } else {
    // remainder of big chunk -> unnormalized partial2 into P2 + stats2
    attn_stream(qtB, x, 32 - 2 * j, false, b, h, w, lane, Qb, Kgb, Vgb,
                P2 + (size_t)cid * 8192, 64,
                stats2 + cid * 256, Ks, Vs);
  }
}

// ---------------- merge: LSE-combine split big chunks ----------------

__global__ __launch_bounds__(256) void merge_kernel(
    unsigned short* __restrict__ Ob, const unsigned short* __restrict__ P2,
    const float* __restrict__ stats1, const float* __restrict__ stats2) {
  const int cid = blockIdx.x;                 // 256
  const int bh = cid >> 3, j = cid & 7, qt = 15 - j;
  const int b = bh >> 4, h = bh & 15;
  const int tid = threadIdx.x;
  const int r = tid >> 1, ch = (tid & 1) * 32;

  const float m1 = stats1[cid * 256 + r * 2], l1 = stats1[cid * 256 + r * 2 + 1];
  const float m2 = stats2[cid * 256 + r * 2], l2 = stats2[cid * 256 + r * 2 + 1];
  const float M = fmaxf(m1, m2);
  const float a1 = fexp2(m1 - M), a2 = fexp2(m2 - M);
  const float invL = 1.0f / (l1 * a1 + l2 * a2);
  const float c1 = a1 * invL, c2 = a2 * invL;

  unsigned short* o1 = Ob + (size_t)(b * 2048 + qt * 128 + r) * 1024 + h * 64 + ch;
  const unsigned short* o2 = P2 + (size_t)cid * 8192 + r * 64 + ch;
#pragma unroll
  for (int i = 0; i < 32; i += 8) {
    int4v v1 = *(const int4v*)(o1 + i);
    int4v v2 = *(const int4v*)(o2 + i);
    int4v ro;
#pragma unroll
    for (int k = 0; k < 4; ++k) {
      unsigned u1 = (unsigned)v1[k], u2 = (unsigned)v2[k];
      float lo = b2f((unsigned short)u1) * c1 + b2f((unsigned short)u2) * c2;
      float hi = b2f((unsigned short)(u1 >> 16)) * c1 + b2f((unsigned short)(u2 >> 16)) * c2;
      ro[k] = (int)pk2b(lo, hi);
    }
    *(int4v*)(o1 + i) = ro;
  }
}

// ---------------- launch ----------------

extern "C" void kernel_launch(void* const* d_in, const int* in_sizes, int n_in,
                              void* d_out, int out_size, void* d_ws, size_t ws_size,
                              hipStream_t stream) {
  (void)in_sizes; (void)n_in; (void)out_size; (void)ws_size;
  const float* x  = (const float*)d_in[0];
  const int*  tp  = (const int*)d_in[1];
  const float* Wq = (const float*)d_in[2];
  const float* Wk = (const float*)d_in[3];
  const float* Wv = (const float*)d_in[4];
  const float* Wo = (const float*)d_in[5];
  float* out = (float*)d_out;

  char* ws = (char*)d_ws;
  unsigned short* xb    = (unsigned short*)(ws);                       // 8MB
  unsigned short* Ob    = (unsigned short*)(ws);                       // reuses xb
  unsigned short* Wqkvb = (unsigned short*)(ws + (8ull << 20));        // 6MB
  unsigned short* P2    = (unsigned short*)(ws + (8ull << 20));        // reuses Wqkvb (4MB)
  unsigned short* Wob   = (unsigned short*)(ws + (14ull << 20));       // 2MB
  unsigned short* Qb    = (unsigned short*)(ws + (16ull << 20));       // 8MB
  unsigned short* Kb    = (unsigned short*)(ws + (24ull << 20));       // 8MB
  unsigned short* VbT   = (unsigned short*)(ws + (32ull << 20));       // 8MB
  float* cosT   = (float*)(ws + (40ull << 20));                        // 256KB
  float* sinT   = (float*)(ws + (40ull << 20) + 262144);               // 256KB
  float* stats1 = (float*)(ws + (40ull << 20));                        // reuses cosT
  float* stats2 = (float*)(ws + (40ull << 20) + 262144);               // reuses sinT

  prep_kernel<<<8256, 256, 0, stream>>>(x, Wq, Wk, Wv, Wo, tp, xb, Wqkvb, Wob, cosT, sinT);
  gemm_qkv_kernel<<<256, 512, 0, stream>>>(xb, Wqkvb, Qb, Kb, VbT, cosT, sinT);
  attn_kernel<<<dim3(32, 16), 256, 0, stream>>>(Qb, Kb, VbT, Ob, P2, stats1, stats2);
  merge_kernel<<<256, 256, 0, stream>>>(Ob, P2, stats1, stats2);
  gemm_out_kernel<<<256, 256, 0, stream>>>(Ob, Wob, out);
}

// Round 16
// 103.597 us; speedup vs baseline: 1.2046x; 1.0225x over previous
//
#include <hip/hip_runtime.h>
#include <hip/hip_bf16.h>

// MHA forward: b=2, s=2048, d=1024, h=16, dk=64. fp32 in/out, bf16 MFMA internally.
// ws layout (40.5 MB):
//   0      : xb [4096][1024] bf16 (8MB)  -- dead after gemm_qkv, reused as Ob (attn out)
//   8 MB   : Wqkvb [3072][1024] bf16 (6MB) -- dead after gemm_qkv, reused as P2 (4MB)
//   14 MB  : Wob [1024][1024] bf16 (2MB)
//   16 MB  : Qb [4096][1024] bf16 (8MB)  (RoPE'd, log2-domain scale)
//   24 MB  : Kb [4096][1024] bf16 (8MB)  (RoPE'd)
//   32 MB  : VbT [32 bh][64 dk][2048 seq] bf16 (8MB)
//   40 MB  : cosT/sinT (512KB) -- dead after gemm_qkv, reused as stats1/stats2

typedef __attribute__((ext_vector_type(8))) __bf16 bf16x8;
typedef __attribute__((ext_vector_type(4))) float f32x4;
typedef __attribute__((ext_vector_type(16))) float f32x16;
typedef __attribute__((ext_vector_type(4))) int int4v;
typedef __attribute__((ext_vector_type(2))) unsigned int uint2v;

#define MFMA16(a, b, c) __builtin_amdgcn_mfma_f32_16x16x32_bf16(a, b, c, 0, 0, 0)
#define MFMA32(a, b, c) __builtin_amdgcn_mfma_f32_32x32x16_bf16(a, b, c, 0, 0, 0)

__device__ inline unsigned short f2b(float f) {
  unsigned u = __builtin_bit_cast(unsigned, f);
  u = (u + 0x7FFF + ((u >> 16) & 1)) >> 16;   // RNE, finite inputs only
  return (unsigned short)u;
}

__device__ inline float b2f(unsigned short u) {
  return __builtin_bit_cast(float, ((unsigned)u) << 16);
}

__device__ inline unsigned pk2b(float lo, float hi) {
  return (unsigned)f2b(lo) | ((unsigned)f2b(hi) << 16);
}

__device__ inline unsigned cvtpk(float lo, float hi) {
  unsigned r;
  asm("v_cvt_pk_bf16_f32 %0, %1, %2" : "=v"(r) : "v"(lo), "v"(hi));
  return r;
}

__device__ inline void plswap(unsigned a, unsigned b, unsigned& o0, unsigned& o1) {
#if __has_builtin(__builtin_amdgcn_permlane32_swap)
  auto r = __builtin_amdgcn_permlane32_swap(a, b, false, false);
  o0 = r[0];
  o1 = r[1];
#else
  unsigned sa = (unsigned)__shfl_xor((int)a, 32, 64);
  unsigned sb = (unsigned)__shfl_xor((int)b, 32, 64);
  bool hi = (threadIdx.x & 32) != 0;
  o0 = hi ? sb : a;
  o1 = hi ? b : sa;
#endif
}

__device__ inline float fexp2(float x) {
#if __has_builtin(__builtin_amdgcn_exp2f)
  return __builtin_amdgcn_exp2f(x);
#else
  return exp2f(x);
#endif
}

// ---------------- fused prep: 8 elems/thread ----------------

__device__ inline void cvt8(const float* __restrict__ s, unsigned short* __restrict__ d,
                            int i, float sc) {
  float4 v0 = *(const float4*)(s + i);
  float4 v1 = *(const float4*)(s + i + 4);
  int4v p;
  p[0] = (int)pk2b(v0.x * sc, v0.y * sc);
  p[1] = (int)pk2b(v0.z * sc, v0.w * sc);
  p[2] = (int)pk2b(v1.x * sc, v1.y * sc);
  p[3] = (int)pk2b(v1.z * sc, v1.w * sc);
  *(int4v*)(d + i) = p;
}

__global__ __launch_bounds__(256) void prep_kernel(
    const float* __restrict__ x, const float* __restrict__ Wq,
    const float* __restrict__ Wk, const float* __restrict__ Wv,
    const float* __restrict__ Wo, const int* __restrict__ tp,
    unsigned short* __restrict__ xb, unsigned short* __restrict__ Wqkvb,
    unsigned short* __restrict__ Wob, float* __restrict__ cosT,
    float* __restrict__ sinT) {
  int t = blockIdx.x * 256 + threadIdx.x;
  if (t < 524288) {
    cvt8(x, xb, t * 8, 1.0f);
  } else if (t < 655360) {
    cvt8(Wq, Wqkvb, (t - 524288) * 8, 0.18033688f);   // (1/8)*log2(e)
  } else if (t < 786432) {
    cvt8(Wk, Wqkvb + 1048576, (t - 655360) * 8, 1.0f);
  } else if (t < 917504) {
    cvt8(Wv, Wqkvb + 2097152, (t - 786432) * 8, 1.0f);
  } else if (t < 1048576) {
    cvt8(Wo, Wob, (t - 917504) * 8, 1.0f);
  } else {
    int base = (t - 1048576) * 8;
#pragma unroll
    for (int j = 0; j < 8; ++j) {
      int idx = base + j;
      int p = idx >> 5, i = idx & 31;
      float pos = (float)tp[p];
      float freq = powf(10000.0f, -(float)i / 32.0f);
      float ang = pos * freq;
      cosT[idx] = cosf(ang);
      sinT[idx] = sinf(ang);
    }
  }
}

// ---------------- GEMM 1 staging: 256x64 A + 192x64 B, xor-swizzled, B 32-group-permuted --

__device__ __forceinline__ void g_stage_qkv(const unsigned short* __restrict__ A,
                                            const unsigned short* __restrict__ B,
                                            unsigned short* __restrict__ As,
                                            unsigned short* __restrict__ Bs,
                                            int m0, int n0, int k0, int w, int lane) {
  const int srow = lane >> 3;
  const int schunk = (lane & 7) ^ srow;          // inverse swizzle on global source
#pragma unroll
  for (int c = 0; c < 4; ++c) {                  // A: 8 waves x 32 rows
    const int rb = w * 32 + c * 8;
    const unsigned short* ga = A + (size_t)(m0 + rb + srow) * 1024 + k0 + schunk * 8;
    __builtin_amdgcn_global_load_lds(
        (const __attribute__((address_space(1))) void*)ga,
        (__attribute__((address_space(3))) void*)(As + rb * 64), 16, 0, 0);
  }
#pragma unroll
  for (int c = 0; c < 3; ++c) {                  // B: 8 waves x 24 rows
    const int rb = w * 24 + c * 8;
    const int rl = rb + srow;
    const int rB = n0 + (rl & 224) + ((rl & 15) << 1) + ((rl >> 4) & 1);  // perm per 32-group
    const unsigned short* gb = B + (size_t)rB * 1024 + k0 + schunk * 8;
    __builtin_amdgcn_global_load_lds(
        (const __attribute__((address_space(1))) void*)gb,
        (__attribute__((address_space(3))) void*)(Bs + rb * 64), 16, 0, 0);
  }
}

// ---------------- GEMM 1: QKV projection + RoPE epilogue ----------------
// 256x192 tile, 8 waves (4M x 2N, per-wave 64x96), BK=64, 2-buf counted vmcnt(7).
// Grid = 256 blocks = exactly 1 round. LDS 112KB, 2 waves/SIMD.

__global__ __launch_bounds__(512, 2) void gemm_qkv_kernel(
    const unsigned short* __restrict__ A,    // xb
    const unsigned short* __restrict__ B,    // Wqkvb
    unsigned short* __restrict__ Qb, unsigned short* __restrict__ Kb,
    unsigned short* __restrict__ VbT,        // [32][64][2048]
    const float* __restrict__ cosT, const float* __restrict__ sinT) {
  __shared__ unsigned short As[2][256 * 64];  // 64KB
  __shared__ unsigned short Bs[2][192 * 64];  // 48KB
  const int bid = blockIdx.x;
  const int xcd = bid & 7, q = bid >> 3;         // q in [0,32)
  const int mg = xcd >> 1, ng = xcd & 1;
  const int m0 = (mg * 4 + (q & 3)) * 256;
  const int n0 = (ng * 8 + (q >> 2)) * 192;
  const int tid = threadIdx.x, w = tid >> 6, lane = tid & 63;
  const int l15 = lane & 15, l4 = lane >> 4;
  const int wr = w & 3, wc = w >> 2;             // 4M x 2N

  f32x4 acc[4][6] = {};

  g_stage_qkv(A, B, As[0], Bs[0], m0, n0, 0, w, lane);   // 7 loads in flight

  int cur = 0;
  for (int k0 = 0; k0 < 1024; k0 += 64) {
    __builtin_amdgcn_s_barrier();                        // readers of buf[cur^1] done
    if (k0 + 64 < 1024) {
      g_stage_qkv(A, B, As[cur ^ 1], Bs[cur ^ 1], m0, n0, k0 + 64, w, lane);
      asm volatile("s_waitcnt vmcnt(7)" ::: "memory");   // stage(k) landed; stage(k+1) flies
    } else {
      asm volatile("s_waitcnt vmcnt(0)" ::: "memory");
    }
    __builtin_amdgcn_sched_barrier(0);

    const unsigned short* as = As[cur];
    const unsigned short* bs = Bs[cur];
#pragma unroll
    for (int kk = 0; kk < 2; ++kk) {
      bf16x8 af[4], bfr[6];
#pragma unroll
      for (int m = 0; m < 4; m++) {
        const int row = wr * 64 + m * 16 + l15;
        af[m] = *(const bf16x8*)(&as[row * 64 + (((kk * 4 + l4) ^ (l15 & 7)) * 8)]);
      }
#pragma unroll
      for (int n = 0; n < 6; n++) {
        const int row = wc * 96 + n * 16 + l15;
        bfr[n] = *(const bf16x8*)(&bs[row * 64 + (((kk * 4 + l4) ^ (l15 & 7)) * 8)]);
      }
#pragma unroll
      for (int m = 0; m < 4; m++)
#pragma unroll
        for (int n = 0; n < 6; n++)
          acc[m][n] = MFMA16(af[m], bfr[n], acc[m][n]);
    }
    cur ^= 1;
  }

  // epilogue: frag-pair (2k,2k+1) = output cols (g, g+1), g = n0 + wc*96 + k*32 + 2*l15.
#pragma unroll
  for (int k = 0; k < 3; k++) {
    const int gcol = n0 + wc * 96 + k * 32 + 2 * l15;
    const int region = gcol >> 10;
    if (region < 2) {
      unsigned short* dst = (region == 0) ? Qb : Kb;
      const int col = gcol & 1023;
      const int pi = (gcol & 63) >> 1;
#pragma unroll
      for (int m = 0; m < 4; m++) {
        const int row0 = m0 + wr * 64 + m * 16 + l4 * 4;
#pragma unroll
        for (int r = 0; r < 4; r++) {
          const int pos = (row0 + r) & 2047;
          float c = cosT[pos * 32 + pi], s = sinT[pos * 32 + pi];
          float v0 = acc[m][2 * k][r], v1 = acc[m][2 * k + 1][r];
          float r1 = fmaf(v0, c, -v1 * s);
          float r2 = fmaf(v1, c, v0 * s);
          *(unsigned*)(dst + (size_t)(row0 + r) * 1024 + col) = pk2b(r1, r2);
        }
      }
    } else {
      const int dkg = gcol - 2048;
      const int h = dkg >> 6, dk = dkg & 63;
#pragma unroll
      for (int m = 0; m < 4; m++) {
        const int row0 = m0 + wr * 64 + m * 16 + l4 * 4;
        const int bb = row0 >> 11, seq = row0 & 2047;
        unsigned short* vp = VbT + (size_t)(bb * 16 + h) * 131072 + dk * 2048 + seq;
        uint2v e = {pk2b(acc[m][2 * k][0], acc[m][2 * k][1]),
                    pk2b(acc[m][2 * k][2], acc[m][2 * k][3])};
        *(uint2v*)vp = e;
        uint2v o = {pk2b(acc[m][2 * k + 1][0], acc[m][2 * k + 1][1]),
                    pk2b(acc[m][2 * k + 1][2], acc[m][2 * k + 1][3])};
        *(uint2v*)(vp + 2048) = o;
      }
    }
  }
}

// ---------------- GEMM 2 staging (8 waves, BK=64, xor-swizzled, B 32-group-permuted) ----

__device__ __forceinline__ void g_stage_out(const unsigned short* __restrict__ A,
                                            const unsigned short* __restrict__ B,
                                            unsigned short* __restrict__ As,
                                            unsigned short* __restrict__ Bs,
                                            int m0, int n0, int k0, int w, int lane) {
  const int srow = lane >> 3;
  const int schunk = (lane & 7) ^ srow;          // inverse swizzle on global source
#pragma unroll
  for (int c = 0; c < 2; ++c) {                  // A: 8 waves x 16 rows
    const int rb = w * 16 + c * 8;
    const unsigned short* ga = A + (size_t)(m0 + rb + srow) * 1024 + k0 + schunk * 8;
    __builtin_amdgcn_global_load_lds(
        (const __attribute__((address_space(1))) void*)ga,
        (__attribute__((address_space(3))) void*)(As + rb * 64), 16, 0, 0);
    const int rl = rb + srow;
    const int rB = n0 + (rl & 96) + ((rl & 15) << 1) + ((rl >> 4) & 1);
    const unsigned short* gb = B + (size_t)rB * 1024 + k0 + schunk * 8;
    __builtin_amdgcn_global_load_lds(
        (const __attribute__((address_space(1))) void*)gb,
        (__attribute__((address_space(3))) void*)(Bs + rb * 64), 16, 0, 0);
  }
}

// ---------------- GEMM 2: output projection, 8 waves (2M x 4N), counted vmcnt ----------

__global__ __launch_bounds__(512, 2) void gemm_out_kernel(
    const unsigned short* __restrict__ A,    // Ob [4096][1024]
    const unsigned short* __restrict__ B,    // Wob [1024][1024]
    float* __restrict__ out) {
  __shared__ unsigned short As[2][128 * 64];
  __shared__ unsigned short Bs[2][128 * 64];
  const int bid = blockIdx.x;
  const int sw = (bid & 7) * 32 + (bid >> 3);
  const int n0 = (sw % 8) * 128, m0 = (sw / 8) * 128;
  const int tid = threadIdx.x, w = tid >> 6, lane = tid & 63;
  const int l15 = lane & 15, l4 = lane >> 4;
  const int wr = w >> 2, wc = w & 3;             // 2M x 4N, per-wave 64x32

  f32x4 acc[4][2] = {};

  g_stage_out(A, B, As[0], Bs[0], m0, n0, 0, w, lane);   // 4 loads in flight

  int cur = 0;
  for (int k0 = 0; k0 < 1024; k0 += 64) {
    __builtin_amdgcn_s_barrier();
    if (k0 + 64 < 1024) {
      g_stage_out(A, B, As[cur ^ 1], Bs[cur ^ 1], m0, n0, k0 + 64, w, lane);
      asm volatile("s_waitcnt vmcnt(4)" ::: "memory");
    } else {
      asm volatile("s_waitcnt vmcnt(0)" ::: "memory");
    }
    __builtin_amdgcn_sched_barrier(0);

    const unsigned short* as = As[cur];
    const unsigned short* bs = Bs[cur];
#pragma unroll
    for (int kk = 0; kk < 2; ++kk) {
      bf16x8 af[4], bfr[2];
#pragma unroll
      for (int m = 0; m < 4; m++) {
        const int row = wr * 64 + m * 16 + l15;
        af[m] = *(const bf16x8*)(&as[row * 64 + (((kk * 4 + l4) ^ (l15 & 7)) * 8)]);
      }
#pragma unroll
      for (int n = 0; n < 2; n++) {
        const int row = wc * 32 + n * 16 + l15;
        bfr[n] = *(const bf16x8*)(&bs[row * 64 + (((kk * 4 + l4) ^ (l15 & 7)) * 8)]);
      }
#pragma unroll
      for (int m = 0; m < 4; m++)
#pragma unroll
        for (int n = 0; n < 2; n++)
          acc[m][n] = MFMA16(af[m], bfr[n], acc[m][n]);
    }
    cur ^= 1;
  }

  // frag pair (0,1) = cols (c, c+1), c = n0 + wc*32 + 2*l15
#pragma unroll
  for (int m = 0; m < 4; m++) {
    const int row0 = m0 + wr * 64 + m * 16 + l4 * 4;
    const int col = n0 + wc * 32 + 2 * l15;
#pragma unroll
    for (int r = 0; r < 4; r++) {
      float2 v = {acc[m][0][r], acc[m][1][r]};
      *(float2*)(out + (size_t)(row0 + r) * 1024 + col) = v;
    }
  }
}

// ---------------- Flash attention: 512 equal 17-tile blocks + LSE merge ----------------

__device__ __forceinline__ void stage_tiles(const unsigned short* __restrict__ Kgb,
                                            const unsigned short* __restrict__ Vgb,
                                            unsigned short* KsBuf, unsigned short* VsBuf,
                                            int kv0, int w, int lane) {
#pragma unroll
  for (int c = 0; c < 2; ++c) {
    const int rowbase = w * 16 + c * 8;
    const int row = rowbase + (lane >> 3);
    const int chunk = (lane & 7) ^ (lane >> 3);    // inverse swizzle on global source
    const unsigned short* gk = Kgb + (size_t)(kv0 + row) * 1024 + chunk * 8;
    __builtin_amdgcn_global_load_lds(
        (const __attribute__((address_space(1))) void*)gk,
        (__attribute__((address_space(3))) void*)(KsBuf + rowbase * 64), 16, 0, 0);
    const unsigned short* gv = Vgb + (size_t)row * 2048 + kv0 + chunk * 8;
    __builtin_amdgcn_global_load_lds(
        (const __attribute__((address_space(1))) void*)gv,
        (__attribute__((address_space(3))) void*)(VsBuf + rowbase * 64), 16, 0, 0);
  }
}

__device__ __forceinline__ void attn_stream(
    int qt, int t0, int t1, bool finalize,
    int b, int h, int w, int lane,
    const unsigned short* __restrict__ Qb,
    const unsigned short* __restrict__ Kgb,
    const unsigned short* __restrict__ Vgb,
    unsigned short* __restrict__ outBase, int ostride,
    float* __restrict__ statsOut,
    unsigned short (*Ks)[64 * 64], unsigned short (*Vs)[64 * 64]) {
  const int l31 = lane & 31, l32 = lane >> 5;
  const int sw = l31 & 7;

  const unsigned short* qptr =
      Qb + (size_t)(b * 2048 + qt * 128 + w * 32 + l31) * 1024 + h * 64 + l32 * 8;
  bf16x8 qa[4];
#pragma unroll
  for (int kk = 0; kk < 4; ++kk) qa[kk] = *(const bf16x8*)(qptr + kk * 16);

  f32x16 oacc[2] = {};
  float m = -3e38f, l = 0.f;

  stage_tiles(Kgb, Vgb, Ks[0], Vs[0], t0 * 64, w, lane);
  stage_tiles(Kgb, Vgb, Ks[1], Vs[1], (t0 + 1) * 64, w, lane);

  int ib = 0, is_ = 2;
  for (int t = t0; t < t1; ++t) {
    if (t < t1 - 1) {
      asm volatile("s_waitcnt vmcnt(4)" ::: "memory");
    } else {
      asm volatile("s_waitcnt vmcnt(0)" ::: "memory");
    }
    __builtin_amdgcn_s_barrier();
    __builtin_amdgcn_sched_barrier(0);
    if (t + 2 < t1)
      stage_tiles(Kgb, Vgb, Ks[is_], Vs[is_], (t + 2) * 64, w, lane);

    // QK^T swapped: St = mfma32(K_frag, Q_frag) -> S^T[kv][q], q = l31
    const char* ksb = (const char*)Ks[ib];
    f32x16 st[2];
    __builtin_amdgcn_s_setprio(1);
#pragma unroll
    for (int f = 0; f < 2; ++f) {
      const char* kb = ksb + (f * 32 + l31) * 128;
      f32x16 z = {};
#pragma unroll
      for (int kk = 0; kk < 4; ++kk) {
        bf16x8 kf = *(const bf16x8*)(kb + ((((kk << 1) | l32) ^ sw) * 16));
        z = MFMA32(kf, qa[kk], z);
      }
      st[f] = z;
    }
    __builtin_amdgcn_s_setprio(0);

    // causal mask (diagonal tiles only; prefix streams never trigger this)
    if (t >= 2 * qt + (w >> 1)) {
      const int qg = qt * 128 + w * 32 + l31;
      const int kvb = t * 64 + 4 * l32;
#pragma unroll
      for (int f = 0; f < 2; ++f)
#pragma unroll
        for (int reg = 0; reg < 16; ++reg) {
          int kv = kvb + 32 * f + (reg & 3) + 8 * (reg >> 2);
          if (kv > qg) st[f][reg] = -3e38f;
        }
    }

    // row max: in-register tree + 1 swap across lane halves
    float a8[8];
#pragma unroll
    for (int j = 0; j < 8; ++j)
      a8[j] = fmaxf(fmaxf(st[0][j], st[0][j + 8]), fmaxf(st[1][j], st[1][j + 8]));
    float pm = fmaxf(fmaxf(fmaxf(a8[0], a8[1]), fmaxf(a8[2], a8[3])),
                     fmaxf(fmaxf(a8[4], a8[5]), fmaxf(a8[6], a8[7])));
    pm = fmaxf(pm, __shfl_xor(pm, 32, 64));

    // defer-max: rescale only when running max grew by > 8 (log2 domain)
    if (!__all(pm - m <= 8.0f)) {
      float mn = fmaxf(m, pm);
      float al = fexp2(m - mn);
      l *= al;
#pragma unroll
      for (int df = 0; df < 2; ++df)
#pragma unroll
        for (int reg = 0; reg < 16; ++reg) oacc[df][reg] *= al;
      m = mn;
    }

    // p = exp2(s - m), pack to bf16 pairs
    unsigned pku[2][4][2];
    float rs0 = 0.f, rs1 = 0.f;
#pragma unroll
    for (int f = 0; f < 2; ++f)
#pragma unroll
      for (int rr = 0; rr < 4; ++rr)
#pragma unroll
        for (int i = 0; i < 2; ++i) {
          float p0 = fexp2(st[f][4 * rr + 2 * i] - m);
          float p1 = fexp2(st[f][4 * rr + 2 * i + 1] - m);
          rs0 += p0; rs1 += p1;
          pku[f][rr][i] = cvtpk(p0, p1);
        }
    float rs = rs0 + rs1;
    rs += __shfl_xor(rs, 32, 64);
    l += rs;

    // redistribute P^T into B-operand frags via permlane32_swap
    union FB { unsigned u[4]; bf16x8 v; };
    FB pfrag[4];
#pragma unroll
    for (int kk = 0; kk < 4; ++kk) {
      const int f = kk >> 1, kl = kk & 1;
      unsigned o00, o10, o01, o11;
      plswap(pku[f][2 * kl][0], pku[f][2 * kl + 1][0], o00, o10);
      plswap(pku[f][2 * kl][1], pku[f][2 * kl + 1][1], o01, o11);
      pfrag[kk].u[0] = o00; pfrag[kk].u[1] = o01;
      pfrag[kk].u[2] = o10; pfrag[kk].u[3] = o11;
    }

    // PV swapped: O^T[d][q] += mfma32(V^T_frag, P^T_frag)
    const char* vsb = (const char*)Vs[ib];
    __builtin_amdgcn_s_setprio(1);
#pragma unroll
    for (int df = 0; df < 2; ++df) {
      const char* vb = vsb + (df * 32 + l31) * 128;
#pragma unroll
      for (int kk = 0; kk < 4; ++kk) {
        bf16x8 vf = *(const bf16x8*)(vb + ((((kk << 1) | l32) ^ sw) * 16));
        oacc[df] = MFMA32(vf, pfrag[kk].v, oacc[df]);
      }
    }
    __builtin_amdgcn_s_setprio(0);

    ib = (ib == 2) ? 0 : ib + 1;
    is_ = (is_ == 2) ? 0 : is_ + 1;
  }

  // output: normalized (final) or raw partial (unnormalized) + stats
  const float sc = finalize ? (1.0f / l) : 1.0f;
  unsigned short* ob = outBase + (size_t)(w * 32 + l31) * ostride + 4 * l32;
#pragma unroll
  for (int df = 0; df < 2; ++df)
#pragma unroll
    for (int rr = 0; rr < 4; ++rr)
#pragma unroll
      for (int i = 0; i < 2; ++i) {
        *(unsigned*)(ob + df * 32 + rr * 8 + 2 * i) =
            pk2b(oacc[df][4 * rr + 2 * i] * sc, oacc[df][4 * rr + 2 * i + 1] * sc);
      }
  if (!finalize && l32 == 0) {
    float2 st2 = {m, l};
    *(float2*)(statsOut + (w * 32 + l31) * 2) = st2;
  }
}

__global__ __launch_bounds__(256, 2) void attn_kernel(
    const unsigned short* __restrict__ Qb,
    const unsigned short* __restrict__ Kb,
    const unsigned short* __restrict__ VbT,   // [32][64][2048]
    unsigned short* __restrict__ Ob,
    unsigned short* __restrict__ P2,          // [256][128][64] partial2
    float* __restrict__ stats1, float* __restrict__ stats2) {
  __shared__ unsigned short Ks[3][64 * 64];
  __shared__ unsigned short Vs[3][64 * 64];
  const int bh = blockIdx.x;                  // fastest -> same bh lands on one XCD
  const int y = blockIdx.y;                   // 0..15
  const int j = y >> 1, half = y & 1;
  const int b = bh >> 4, h = bh & 15;
  const int qtB = 15 - j;
  const int x = 15 - 2 * j;                   // split point of big chunk
  const int cid = bh * 8 + j;
  const int tid = threadIdx.x, w = tid >> 6, lane = tid & 63;

  const unsigned short* Kgb = Kb + (size_t)b * 2048 * 1024 + h * 64;
  const unsigned short* Vgb = VbT + (size_t)bh * 131072;

  if (half == 0) {
    // prefix of big chunk -> unnormalized partial1 into Ob slot + stats1
    attn_stream(qtB, 0, x, false, b, h, w, lane, Qb, Kgb, Vgb,
                Ob + (size_t)(b * 2048 + qtB * 128) * 1024 + h * 64, 1024,
                stats1 + cid * 256, Ks, Vs);
    __syncthreads();
    // whole small chunk -> final
    attn_stream(j, 0, 2 * j + 2, true, b, h, w, lane, Qb, Kgb, Vgb,
                Ob + (size_t)(b * 2048 + j * 128) * 1024 + h * 64, 1024,
                nullptr, Ks, Vs);
  } else {
    // remainder of big chunk -> unnormalized partial2 into P2 + stats2
    attn_stream(qtB, x, 32 - 2 * j, false, b, h, w, lane, Qb, Kgb, Vgb,
                P2 + (size_t)cid * 8192, 64,
                stats2 + cid * 256, Ks, Vs);
  }
}

// ---------------- merge: LSE-combine split big chunks ----------------

__global__ __launch_bounds__(256) void merge_kernel(
    unsigned short* __restrict__ Ob, const unsigned short* __restrict__ P2,
    const float* __restrict__ stats1, const float* __restrict__ stats2) {
  const int cid = blockIdx.x;                 // 256
  const int bh = cid >> 3, j = cid & 7, qt = 15 - j;
  const int b = bh >> 4, h = bh & 15;
  const int tid = threadIdx.x;
  const int r = tid >> 1, ch = (tid & 1) * 32;

  const float m1 = stats1[cid * 256 + r * 2], l1 = stats1[cid * 256 + r * 2 + 1];
  const float m2 = stats2[cid * 256 + r * 2], l2 = stats2[cid * 256 + r * 2 + 1];
  const float M = fmaxf(m1, m2);
  const float a1 = fexp2(m1 - M), a2 = fexp2(m2 - M);
  const float invL = 1.0f / (l1 * a1 + l2 * a2);
  const float c1 = a1 * invL, c2 = a2 * invL;

  unsigned short* o1 = Ob + (size_t)(b * 2048 + qt * 128 + r) * 1024 + h * 64 + ch;
  const unsigned short* o2 = P2 + (size_t)cid * 8192 + r * 64 + ch;
#pragma unroll
  for (int i = 0; i < 32; i += 8) {
    int4v v1 = *(const int4v*)(o1 + i);
    int4v v2 = *(const int4v*)(o2 + i);
    int4v ro;
#pragma unroll
    for (int k = 0; k < 4; ++k) {
      unsigned u1 = (unsigned)v1[k], u2 = (unsigned)v2[k];
      float lo = b2f((unsigned short)u1) * c1 + b2f((unsigned short)u2) * c2;
      float hi = b2f((unsigned short)(u1 >> 16)) * c1 + b2f((unsigned short)(u2 >> 16)) * c2;
      ro[k] = (int)pk2b(lo, hi);
    }
    *(int4v*)(o1 + i) = ro;
  }
}

// ---------------- launch ----------------

extern "C" void kernel_launch(void* const* d_in, const int* in_sizes, int n_in,
                              void* d_out, int out_size, void* d_ws, size_t ws_size,
                              hipStream_t stream) {
  (void)in_sizes; (void)n_in; (void)out_size; (void)ws_size;
  const float* x  = (const float*)d_in[0];
  const int*  tp  = (const int*)d_in[1];
  const float* Wq = (const float*)d_in[2];
  const float* Wk = (const float*)d_in[3];
  const float* Wv = (const float*)d_in[4];
  const float* Wo = (const float*)d_in[5];
  float* out = (float*)d_out;

  char* ws = (char*)d_ws;
  unsigned short* xb    = (unsigned short*)(ws);                       // 8MB
  unsigned short* Ob    = (unsigned short*)(ws);                       // reuses xb
  unsigned short* Wqkvb = (unsigned short*)(ws + (8ull << 20));        // 6MB
  unsigned short* P2    = (unsigned short*)(ws + (8ull << 20));        // reuses Wqkvb (4MB)
  unsigned short* Wob   = (unsigned short*)(ws + (14ull << 20));       // 2MB
  unsigned short* Qb    = (unsigned short*)(ws + (16ull << 20));       // 8MB
  unsigned short* Kb    = (unsigned short*)(ws + (24ull << 20));       // 8MB
  unsigned short* VbT   = (unsigned short*)(ws + (32ull << 20));       // 8MB
  float* cosT   = (float*)(ws + (40ull << 20));                        // 256KB
  float* sinT   = (float*)(ws + (40ull << 20) + 262144);               // 256KB
  float* stats1 = (float*)(ws + (40ull << 20));                        // reuses cosT
  float* stats2 = (float*)(ws + (40ull << 20) + 262144);               // reuses sinT

  prep_kernel<<<4128, 256, 0, stream>>>(x, Wq, Wk, Wv, Wo, tp, xb, Wqkvb, Wob, cosT, sinT);
  gemm_qkv_kernel<<<256, 512, 0, stream>>>(xb, Wqkvb, Qb, Kb, VbT, cosT, sinT);
  attn_kernel<<<dim3(32, 16), 256, 0, stream>>>(Qb, Kb, VbT, Ob, P2, stats1, stats2);
  merge_kernel<<<256, 256, 0, stream>>>(Ob, P2, stats1, stats2);
  gemm_out_kernel<<<256, 512, 0, stream>>>(Ob, Wob, out);
}

// Round 17
// 103.543 us; speedup vs baseline: 1.2052x; 1.0005x over previous
//
#include <hip/hip_runtime.h>
#include <hip/hip_bf16.h>

// MHA forward: b=2, s=2048, d=1024, h=16, dk=64. fp32 in/out, bf16 MFMA internally.
// ws layout (40.5 MB):
//   0      : xb [4096][1024] bf16 (8MB)  -- dead after gemm_qkv, reused as Ob (attn out)
//   8 MB   : Wqkvb [3072][1024] bf16 (6MB) -- dead after gemm_qkv, reused as P2 (4MB)
//   14 MB  : Wob [1024][1024] bf16 (2MB)
//   16 MB  : Qb [4096][1024] bf16 (8MB)  (RoPE'd, log2-domain scale)
//   24 MB  : Kb [4096][1024] bf16 (8MB)  (RoPE'd)
//   32 MB  : VbT [32 bh][64 dk][2048 seq] bf16 (8MB)
//   40 MB  : cosT/sinT (512KB) -- dead after gemm_qkv, reused as stats1/stats2

typedef __attribute__((ext_vector_type(8))) __bf16 bf16x8;
typedef __attribute__((ext_vector_type(4))) float f32x4;
typedef __attribute__((ext_vector_type(16))) float f32x16;
typedef __attribute__((ext_vector_type(4))) int int4v;
typedef __attribute__((ext_vector_type(2))) unsigned int uint2v;

#define MFMA16(a, b, c) __builtin_amdgcn_mfma_f32_16x16x32_bf16(a, b, c, 0, 0, 0)
#define MFMA32(a, b, c) __builtin_amdgcn_mfma_f32_32x32x16_bf16(a, b, c, 0, 0, 0)

__device__ inline unsigned short f2b(float f) {
  unsigned u = __builtin_bit_cast(unsigned, f);
  u = (u + 0x7FFF + ((u >> 16) & 1)) >> 16;   // RNE, finite inputs only
  return (unsigned short)u;
}

__device__ inline float b2f(unsigned short u) {
  return __builtin_bit_cast(float, ((unsigned)u) << 16);
}

__device__ inline unsigned pk2b(float lo, float hi) {
  return (unsigned)f2b(lo) | ((unsigned)f2b(hi) << 16);
}

__device__ inline unsigned cvtpk(float lo, float hi) {
  unsigned r;
  asm("v_cvt_pk_bf16_f32 %0, %1, %2" : "=v"(r) : "v"(lo), "v"(hi));
  return r;
}

__device__ inline void plswap(unsigned a, unsigned b, unsigned& o0, unsigned& o1) {
#if __has_builtin(__builtin_amdgcn_permlane32_swap)
  auto r = __builtin_amdgcn_permlane32_swap(a, b, false, false);
  o0 = r[0];
  o1 = r[1];
#else
  unsigned sa = (unsigned)__shfl_xor((int)a, 32, 64);
  unsigned sb = (unsigned)__shfl_xor((int)b, 32, 64);
  bool hi = (threadIdx.x & 32) != 0;
  o0 = hi ? sb : a;
  o1 = hi ? b : sa;
#endif
}

__device__ inline float fexp2(float x) {
#if __has_builtin(__builtin_amdgcn_exp2f)
  return __builtin_amdgcn_exp2f(x);
#else
  return exp2f(x);
#endif
}

// ---------------- fused prep: 8 elems/thread ----------------

__device__ inline void cvt8(const float* __restrict__ s, unsigned short* __restrict__ d,
                            int i, float sc) {
  float4 v0 = *(const float4*)(s + i);
  float4 v1 = *(const float4*)(s + i + 4);
  int4v p;
  p[0] = (int)pk2b(v0.x * sc, v0.y * sc);
  p[1] = (int)pk2b(v0.z * sc, v0.w * sc);
  p[2] = (int)pk2b(v1.x * sc, v1.y * sc);
  p[3] = (int)pk2b(v1.z * sc, v1.w * sc);
  *(int4v*)(d + i) = p;
}

__global__ __launch_bounds__(256) void prep_kernel(
    const float* __restrict__ x, const float* __restrict__ Wq,
    const float* __restrict__ Wk, const float* __restrict__ Wv,
    const float* __restrict__ Wo, const int* __restrict__ tp,
    unsigned short* __restrict__ xb, unsigned short* __restrict__ Wqkvb,
    unsigned short* __restrict__ Wob, float* __restrict__ cosT,
    float* __restrict__ sinT) {
  int t = blockIdx.x * 256 + threadIdx.x;
  if (t < 524288) {
    cvt8(x, xb, t * 8, 1.0f);
  } else if (t < 655360) {
    cvt8(Wq, Wqkvb, (t - 524288) * 8, 0.18033688f);   // (1/8)*log2(e)
  } else if (t < 786432) {
    cvt8(Wk, Wqkvb + 1048576, (t - 655360) * 8, 1.0f);
  } else if (t < 917504) {
    cvt8(Wv, Wqkvb + 2097152, (t - 786432) * 8, 1.0f);
  } else if (t < 1048576) {
    cvt8(Wo, Wob, (t - 917504) * 8, 1.0f);
  } else {
    int base = (t - 1048576) * 8;
#pragma unroll
    for (int j = 0; j < 8; ++j) {
      int idx = base + j;
      int p = idx >> 5, i = idx & 31;
      float pos = (float)tp[p];
      float freq = powf(10000.0f, -(float)i / 32.0f);
      float ang = pos * freq;
      cosT[idx] = cosf(ang);
      sinT[idx] = sinf(ang);
    }
  }
}

// ---------------- GEMM 1 staging: 256x64 A + 192x64 B, xor-swizzled, B 32-group-permuted --

__device__ __forceinline__ void g_stage_qkv(const unsigned short* __restrict__ A,
                                            const unsigned short* __restrict__ B,
                                            unsigned short* __restrict__ As,
                                            unsigned short* __restrict__ Bs,
                                            int m0, int n0, int k0, int w, int lane) {
  const int srow = lane >> 3;
  const int schunk = (lane & 7) ^ srow;          // inverse swizzle on global source
#pragma unroll
  for (int c = 0; c < 4; ++c) {                  // A: 8 waves x 32 rows
    const int rb = w * 32 + c * 8;
    const unsigned short* ga = A + (size_t)(m0 + rb + srow) * 1024 + k0 + schunk * 8;
    __builtin_amdgcn_global_load_lds(
        (const __attribute__((address_space(1))) void*)ga,
        (__attribute__((address_space(3))) void*)(As + rb * 64), 16, 0, 0);
  }
#pragma unroll
  for (int c = 0; c < 3; ++c) {                  // B: 8 waves x 24 rows
    const int rb = w * 24 + c * 8;
    const int rl = rb + srow;
    const int rB = n0 + (rl & 224) + ((rl & 15) << 1) + ((rl >> 4) & 1);  // perm per 32-group
    const unsigned short* gb = B + (size_t)rB * 1024 + k0 + schunk * 8;
    __builtin_amdgcn_global_load_lds(
        (const __attribute__((address_space(1))) void*)gb,
        (__attribute__((address_space(3))) void*)(Bs + rb * 64), 16, 0, 0);
  }
}

// ---------------- GEMM 1: QKV projection + RoPE epilogue ----------------
// 256x192 tile, 8 waves (4M x 2N, per-wave 64x96), BK=64, 2-buf counted vmcnt(7).
// Grid = 256 blocks = exactly 1 round. LDS 112KB, 2 waves/SIMD.

__global__ __launch_bounds__(512, 2) void gemm_qkv_kernel(
    const unsigned short* __restrict__ A,    // xb
    const unsigned short* __restrict__ B,    // Wqkvb
    unsigned short* __restrict__ Qb, unsigned short* __restrict__ Kb,
    unsigned short* __restrict__ VbT,        // [32][64][2048]
    const float* __restrict__ cosT, const float* __restrict__ sinT) {
  __shared__ unsigned short As[2][256 * 64];  // 64KB
  __shared__ unsigned short Bs[2][192 * 64];  // 48KB
  const int bid = blockIdx.x;
  const int xcd = bid & 7, q = bid >> 3;         // q in [0,32)
  const int mg = xcd >> 1, ng = xcd & 1;
  const int m0 = (mg * 4 + (q & 3)) * 256;
  const int n0 = (ng * 8 + (q >> 2)) * 192;
  const int tid = threadIdx.x, w = tid >> 6, lane = tid & 63;
  const int l15 = lane & 15, l4 = lane >> 4;
  const int wr = w & 3, wc = w >> 2;             // 4M x 2N

  f32x4 acc[4][6] = {};

  g_stage_qkv(A, B, As[0], Bs[0], m0, n0, 0, w, lane);   // 7 loads in flight

  int cur = 0;
  for (int k0 = 0; k0 < 1024; k0 += 64) {
    __builtin_amdgcn_s_barrier();                        // readers of buf[cur^1] done
    if (k0 + 64 < 1024) {
      g_stage_qkv(A, B, As[cur ^ 1], Bs[cur ^ 1], m0, n0, k0 + 64, w, lane);
      asm volatile("s_waitcnt vmcnt(7)" ::: "memory");   // stage(k) landed; stage(k+1) flies
    } else {
      asm volatile("s_waitcnt vmcnt(0)" ::: "memory");
    }
    __builtin_amdgcn_sched_barrier(0);

    const unsigned short* as = As[cur];
    const unsigned short* bs = Bs[cur];
#pragma unroll
    for (int kk = 0; kk < 2; ++kk) {
      bf16x8 af[4], bfr[6];
#pragma unroll
      for (int m = 0; m < 4; m++) {
        const int row = wr * 64 + m * 16 + l15;
        af[m] = *(const bf16x8*)(&as[row * 64 + (((kk * 4 + l4) ^ (l15 & 7)) * 8)]);
      }
#pragma unroll
      for (int n = 0; n < 6; n++) {
        const int row = wc * 96 + n * 16 + l15;
        bfr[n] = *(const bf16x8*)(&bs[row * 64 + (((kk * 4 + l4) ^ (l15 & 7)) * 8)]);
      }
#pragma unroll
      for (int m = 0; m < 4; m++)
#pragma unroll
        for (int n = 0; n < 6; n++)
          acc[m][n] = MFMA16(af[m], bfr[n], acc[m][n]);
    }
    cur ^= 1;
  }

  // epilogue: frag-pair (2k,2k+1) = output cols (g, g+1), g = n0 + wc*96 + k*32 + 2*l15.
#pragma unroll
  for (int k = 0; k < 3; k++) {
    const int gcol = n0 + wc * 96 + k * 32 + 2 * l15;
    const int region = gcol >> 10;
    if (region < 2) {
      unsigned short* dst = (region == 0) ? Qb : Kb;
      const int col = gcol & 1023;
      const int pi = (gcol & 63) >> 1;
#pragma unroll
      for (int m = 0; m < 4; m++) {
        const int row0 = m0 + wr * 64 + m * 16 + l4 * 4;
#pragma unroll
        for (int r = 0; r < 4; r++) {
          const int pos = (row0 + r) & 2047;
          float c = cosT[pos * 32 + pi], s = sinT[pos * 32 + pi];
          float v0 = acc[m][2 * k][r], v1 = acc[m][2 * k + 1][r];
          float r1 = fmaf(v0, c, -v1 * s);
          float r2 = fmaf(v1, c, v0 * s);
          *(unsigned*)(dst + (size_t)(row0 + r) * 1024 + col) = pk2b(r1, r2);
        }
      }
    } else {
      const int dkg = gcol - 2048;
      const int h = dkg >> 6, dk = dkg & 63;
#pragma unroll
      for (int m = 0; m < 4; m++) {
        const int row0 = m0 + wr * 64 + m * 16 + l4 * 4;
        const int bb = row0 >> 11, seq = row0 & 2047;
        unsigned short* vp = VbT + (size_t)(bb * 16 + h) * 131072 + dk * 2048 + seq;
        uint2v e = {pk2b(acc[m][2 * k][0], acc[m][2 * k][1]),
                    pk2b(acc[m][2 * k][2], acc[m][2 * k][3])};
        *(uint2v*)vp = e;
        uint2v o = {pk2b(acc[m][2 * k + 1][0], acc[m][2 * k + 1][1]),
                    pk2b(acc[m][2 * k + 1][2], acc[m][2 * k + 1][3])};
        *(uint2v*)(vp + 2048) = o;
      }
    }
  }
}

// ---------------- GEMM 2 staging (8 waves, BK=64, xor-swizzled, B 32-group-permuted) ----

__device__ __forceinline__ void g_stage_out(const unsigned short* __restrict__ A,
                                            const unsigned short* __restrict__ B,
                                            unsigned short* __restrict__ As,
                                            unsigned short* __restrict__ Bs,
                                            int m0, int n0, int k0, int w, int lane) {
  const int srow = lane >> 3;
  const int schunk = (lane & 7) ^ srow;          // inverse swizzle on global source
#pragma unroll
  for (int c = 0; c < 2; ++c) {                  // A: 8 waves x 16 rows
    const int rb = w * 16 + c * 8;
    const unsigned short* ga = A + (size_t)(m0 + rb + srow) * 1024 + k0 + schunk * 8;
    __builtin_amdgcn_global_load_lds(
        (const __attribute__((address_space(1))) void*)ga,
        (__attribute__((address_space(3))) void*)(As + rb * 64), 16, 0, 0);
    const int rl = rb + srow;
    const int rB = n0 + (rl & 96) + ((rl & 15) << 1) + ((rl >> 4) & 1);
    const unsigned short* gb = B + (size_t)rB * 1024 + k0 + schunk * 8;
    __builtin_amdgcn_global_load_lds(
        (const __attribute__((address_space(1))) void*)gb,
        (__attribute__((address_space(3))) void*)(Bs + rb * 64), 16, 0, 0);
  }
}

// ---------------- GEMM 2: output projection, 8 waves (2M x 4N), counted vmcnt ----------

__global__ __launch_bounds__(512, 2) void gemm_out_kernel(
    const unsigned short* __restrict__ A,    // Ob [4096][1024]
    const unsigned short* __restrict__ B,    // Wob [1024][1024]
    float* __restrict__ out) {
  __shared__ unsigned short As[2][128 * 64];
  __shared__ unsigned short Bs[2][128 * 64];
  const int bid = blockIdx.x;
  const int sw = (bid & 7) * 32 + (bid >> 3);
  const int n0 = (sw % 8) * 128, m0 = (sw / 8) * 128;
  const int tid = threadIdx.x, w = tid >> 6, lane = tid & 63;
  const int l15 = lane & 15, l4 = lane >> 4;
  const int wr = w >> 2, wc = w & 3;             // 2M x 4N, per-wave 64x32

  f32x4 acc[4][2] = {};

  g_stage_out(A, B, As[0], Bs[0], m0, n0, 0, w, lane);   // 4 loads in flight

  int cur = 0;
  for (int k0 = 0; k0 < 1024; k0 += 64) {
    __builtin_amdgcn_s_barrier();
    if (k0 + 64 < 1024) {
      g_stage_out(A, B, As[cur ^ 1], Bs[cur ^ 1], m0, n0, k0 + 64, w, lane);
      asm volatile("s_waitcnt vmcnt(4)" ::: "memory");
    } else {
      asm volatile("s_waitcnt vmcnt(0)" ::: "memory");
    }
    __builtin_amdgcn_sched_barrier(0);

    const unsigned short* as = As[cur];
    const unsigned short* bs = Bs[cur];
#pragma unroll
    for (int kk = 0; kk < 2; ++kk) {
      bf16x8 af[4], bfr[2];
#pragma unroll
      for (int m = 0; m < 4; m++) {
        const int row = wr * 64 + m * 16 + l15;
        af[m] = *(const bf16x8*)(&as[row * 64 + (((kk * 4 + l4) ^ (l15 & 7)) * 8)]);
      }
#pragma unroll
      for (int n = 0; n < 2; n++) {
        const int row = wc * 32 + n * 16 + l15;
        bfr[n] = *(const bf16x8*)(&bs[row * 64 + (((kk * 4 + l4) ^ (l15 & 7)) * 8)]);
      }
#pragma unroll
      for (int m = 0; m < 4; m++)
#pragma unroll
        for (int n = 0; n < 2; n++)
          acc[m][n] = MFMA16(af[m], bfr[n], acc[m][n]);
    }
    cur ^= 1;
  }

  // frag pair (0,1) = cols (c, c+1), c = n0 + wc*32 + 2*l15
#pragma unroll
  for (int m = 0; m < 4; m++) {
    const int row0 = m0 + wr * 64 + m * 16 + l4 * 4;
    const int col = n0 + wc * 32 + 2 * l15;
#pragma unroll
    for (int r = 0; r < 4; r++) {
      float2 v = {acc[m][0][r], acc[m][1][r]};
      *(float2*)(out + (size_t)(row0 + r) * 1024 + col) = v;
    }
  }
}

// ---------------- Flash attention: 512 equal 17-tile blocks + LSE merge ----------------
// 4 LDS buffer pairs (64KB, 2 blocks/CU), 3 stages (12 loads) in flight, barrier every
// 2 iterations. Overwrite distance 4 > max skew 2 -> race-free.

__device__ __forceinline__ void stage_tiles(const unsigned short* __restrict__ Kgb,
                                            const unsigned short* __restrict__ Vgb,
                                            unsigned short* KsBuf, unsigned short* VsBuf,
                                            int kv0, int w, int lane) {
#pragma unroll
  for (int c = 0; c < 2; ++c) {
    const int rowbase = w * 16 + c * 8;
    const int row = rowbase + (lane >> 3);
    const int chunk = (lane & 7) ^ (lane >> 3);    // inverse swizzle on global source
    const unsigned short* gk = Kgb + (size_t)(kv0 + row) * 1024 + chunk * 8;
    __builtin_amdgcn_global_load_lds(
        (const __attribute__((address_space(1))) void*)gk,
        (__attribute__((address_space(3))) void*)(KsBuf + rowbase * 64), 16, 0, 0);
    const unsigned short* gv = Vgb + (size_t)row * 2048 + kv0 + chunk * 8;
    __builtin_amdgcn_global_load_lds(
        (const __attribute__((address_space(1))) void*)gv,
        (__attribute__((address_space(3))) void*)(VsBuf + rowbase * 64), 16, 0, 0);
  }
}

__device__ __forceinline__ void attn_stream(
    int qt, int t0, int t1, bool finalize,
    int b, int h, int w, int lane,
    const unsigned short* __restrict__ Qb,
    const unsigned short* __restrict__ Kgb,
    const unsigned short* __restrict__ Vgb,
    unsigned short* __restrict__ outBase, int ostride,
    float* __restrict__ statsOut,
    unsigned short (*Ks)[64 * 64], unsigned short (*Vs)[64 * 64]) {
  const int l31 = lane & 31, l32 = lane >> 5;
  const int sw = l31 & 7;

  const unsigned short* qptr =
      Qb + (size_t)(b * 2048 + qt * 128 + w * 32 + l31) * 1024 + h * 64 + l32 * 8;
  bf16x8 qa[4];
#pragma unroll
  for (int kk = 0; kk < 4; ++kk) qa[kk] = *(const bf16x8*)(qptr + kk * 16);

  f32x16 oacc[2] = {};
  float m = -3e38f, l = 0.f;

  stage_tiles(Kgb, Vgb, Ks[0], Vs[0], t0 * 64, w, lane);
  if (t0 + 1 < t1) stage_tiles(Kgb, Vgb, Ks[1], Vs[1], (t0 + 1) * 64, w, lane);

  for (int t = t0; t < t1; ++t) {
    const int it = t - t0;
    if ((it & 1) == 0) __builtin_amdgcn_s_barrier();     // every 2 iters; skew <= 2 < 4 bufs
    if (t + 2 < t1)
      stage_tiles(Kgb, Vgb, Ks[(it + 2) & 3], Vs[(it + 2) & 3], (t + 2) * 64, w, lane);
    // wait for stage(t): 3 stages in flight steady-state
    if (t + 2 < t1) {
      asm volatile("s_waitcnt vmcnt(8)" ::: "memory");
    } else if (t + 1 < t1) {
      asm volatile("s_waitcnt vmcnt(4)" ::: "memory");
    } else {
      asm volatile("s_waitcnt vmcnt(0)" ::: "memory");
    }
    __builtin_amdgcn_sched_barrier(0);

    // QK^T swapped: St = mfma32(K_frag, Q_frag) -> S^T[kv][q], q = l31
    const char* ksb = (const char*)Ks[it & 3];
    f32x16 st[2];
    __builtin_amdgcn_s_setprio(1);
#pragma unroll
    for (int f = 0; f < 2; ++f) {
      const char* kb = ksb + (f * 32 + l31) * 128;
      f32x16 z = {};
#pragma unroll
      for (int kk = 0; kk < 4; ++kk) {
        bf16x8 kf = *(const bf16x8*)(kb + ((((kk << 1) | l32) ^ sw) * 16));
        z = MFMA32(kf, qa[kk], z);
      }
      st[f] = z;
    }
    __builtin_amdgcn_s_setprio(0);

    // causal mask (diagonal tiles only; prefix streams never trigger this)
    if (t >= 2 * qt + (w >> 1)) {
      const int qg = qt * 128 + w * 32 + l31;
      const int kvb = t * 64 + 4 * l32;
#pragma unroll
      for (int f = 0; f < 2; ++f)
#pragma unroll
        for (int reg = 0; reg < 16; ++reg) {
          int kv = kvb + 32 * f + (reg & 3) + 8 * (reg >> 2);
          if (kv > qg) st[f][reg] = -3e38f;
        }
    }

    // row max: in-register tree + 1 swap across lane halves
    float a8[8];
#pragma unroll
    for (int j = 0; j < 8; ++j)
      a8[j] = fmaxf(fmaxf(st[0][j], st[0][j + 8]), fmaxf(st[1][j], st[1][j + 8]));
    float pm = fmaxf(fmaxf(fmaxf(a8[0], a8[1]), fmaxf(a8[2], a8[3])),
                     fmaxf(fmaxf(a8[4], a8[5]), fmaxf(a8[6], a8[7])));
    pm = fmaxf(pm, __shfl_xor(pm, 32, 64));

    // defer-max: rescale only when running max grew by > 8 (log2 domain)
    if (!__all(pm - m <= 8.0f)) {
      float mn = fmaxf(m, pm);
      float al = fexp2(m - mn);
      l *= al;
#pragma unroll
      for (int df = 0; df < 2; ++df)
#pragma unroll
        for (int reg = 0; reg < 16; ++reg) oacc[df][reg] *= al;
      m = mn;
    }

    // p = exp2(s - m), pack to bf16 pairs
    unsigned pku[2][4][2];
    float rs0 = 0.f, rs1 = 0.f;
#pragma unroll
    for (int f = 0; f < 2; ++f)
#pragma unroll
      for (int rr = 0; rr < 4; ++rr)
#pragma unroll
        for (int i = 0; i < 2; ++i) {
          float p0 = fexp2(st[f][4 * rr + 2 * i] - m);
          float p1 = fexp2(st[f][4 * rr + 2 * i + 1] - m);
          rs0 += p0; rs1 += p1;
          pku[f][rr][i] = cvtpk(p0, p1);
        }
    float rs = rs0 + rs1;
    rs += __shfl_xor(rs, 32, 64);
    l += rs;

    // redistribute P^T into B-operand frags via permlane32_swap
    union FB { unsigned u[4]; bf16x8 v; };
    FB pfrag[4];
#pragma unroll
    for (int kk = 0; kk < 4; ++kk) {
      const int f = kk >> 1, kl = kk & 1;
      unsigned o00, o10, o01, o11;
      plswap(pku[f][2 * kl][0], pku[f][2 * kl + 1][0], o00, o10);
      plswap(pku[f][2 * kl][1], pku[f][2 * kl + 1][1], o01, o11);
      pfrag[kk].u[0] = o00; pfrag[kk].u[1] = o01;
      pfrag[kk].u[2] = o10; pfrag[kk].u[3] = o11;
    }

    // PV swapped: O^T[d][q] += mfma32(V^T_frag, P^T_frag)
    const char* vsb = (const char*)Vs[it & 3];
    __builtin_amdgcn_s_setprio(1);
#pragma unroll
    for (int df = 0; df < 2; ++df) {
      const char* vb = vsb + (df * 32 + l31) * 128;
#pragma unroll
      for (int kk = 0; kk < 4; ++kk) {
        bf16x8 vf = *(const bf16x8*)(vb + ((((kk << 1) | l32) ^ sw) * 16));
        oacc[df] = MFMA32(vf, pfrag[kk].v, oacc[df]);
      }
    }
    __builtin_amdgcn_s_setprio(0);
  }

  // output: normalized (final) or raw partial (unnormalized) + stats
  const float sc = finalize ? (1.0f / l) : 1.0f;
  unsigned short* ob = outBase + (size_t)(w * 32 + l31) * ostride + 4 * l32;
#pragma unroll
  for (int df = 0; df < 2; ++df)
#pragma unroll
    for (int rr = 0; rr < 4; ++rr)
#pragma unroll
      for (int i = 0; i < 2; ++i) {
        *(unsigned*)(ob + df * 32 + rr * 8 + 2 * i) =
            pk2b(oacc[df][4 * rr + 2 * i] * sc, oacc[df][4 * rr + 2 * i + 1] * sc);
      }
  if (!finalize && l32 == 0) {
    float2 st2 = {m, l};
    *(float2*)(statsOut + (w * 32 + l31) * 2) = st2;
  }
}

__global__ __launch_bounds__(256, 2) void attn_kernel(
    const unsigned short* __restrict__ Qb,
    const unsigned short* __restrict__ Kb,
    const unsigned short* __restrict__ VbT,   // [32][64][2048]
    unsigned short* __restrict__ Ob,
    unsigned short* __restrict__ P2,          // [256][128][64] partial2
    float* __restrict__ stats1, float* __restrict__ stats2) {
  __shared__ unsigned short Ks[4][64 * 64];   // 4-deep, 64KB total with Vs
  __shared__ unsigned short Vs[4][64 * 64];
  const int bh = blockIdx.x;                  // fastest -> same bh lands on one XCD
  const int y = blockIdx.y;                   // 0..15
  const int j = y >> 1, half = y & 1;
  const int b = bh >> 4, h = bh & 15;
  const int qtB = 15 - j;
  const int x = 15 - 2 * j;                   // split point of big chunk
  const int cid = bh * 8 + j;
  const int tid = threadIdx.x, w = tid >> 6, lane = tid & 63;

  const unsigned short* Kgb = Kb + (size_t)b * 2048 * 1024 + h * 64;
  const unsigned short* Vgb = VbT + (size_t)bh * 131072;

  if (half == 0) {
    // prefix of big chunk -> unnormalized partial1 into Ob slot + stats1
    attn_stream(qtB, 0, x, false, b, h, w, lane, Qb, Kgb, Vgb,
                Ob + (size_t)(b * 2048 + qtB * 128) * 1024 + h * 64, 1024,
                stats1 + cid * 256, Ks, Vs);
    __syncthreads();
    // whole small chunk -> final
    attn_stream(j, 0, 2 * j + 2, true, b, h, w, lane, Qb, Kgb, Vgb,
                Ob + (size_t)(b * 2048 + j * 128) * 1024 + h * 64, 1024,
                nullptr, Ks, Vs);
  } else {
    // remainder of big chunk -> unnormalized partial2 into P2 + stats2
    attn_stream(qtB, x, 32 - 2 * j, false, b, h, w, lane, Qb, Kgb, Vgb,
                P2 + (size_t)cid * 8192, 64,
                stats2 + cid * 256, Ks, Vs);
  }
}

// ---------------- merge: LSE-combine split big chunks ----------------

__global__ __launch_bounds__(256) void merge_kernel(
    unsigned short* __restrict__ Ob, const unsigned short* __restrict__ P2,
    const float* __restrict__ stats1, const float* __restrict__ stats2) {
  const int cid = blockIdx.x;                 // 256
  const int bh = cid >> 3, j = cid & 7, qt = 15 - j;
  const int b = bh >> 4, h = bh & 15;
  const int tid = threadIdx.x;
  const int r = tid >> 1, ch = (tid & 1) * 32;

  const float m1 = stats1[cid * 256 + r * 2], l1 = stats1[cid * 256 + r * 2 + 1];
  const float m2 = stats2[cid * 256 + r * 2], l2 = stats2[cid * 256 + r * 2 + 1];
  const float M = fmaxf(m1, m2);
  const float a1 = fexp2(m1 - M), a2 = fexp2(m2 - M);
  const float invL = 1.0f / (l1 * a1 + l2 * a2);
  const float c1 = a1 * invL, c2 = a2 * invL;

  unsigned short* o1 = Ob + (size_t)(b * 2048 + qt * 128 + r) * 1024 + h * 64 + ch;
  const unsigned short* o2 = P2 + (size_t)cid * 8192 + r * 64 + ch;
#pragma unroll
  for (int i = 0; i < 32; i += 8) {
    int4v v1 = *(const int4v*)(o1 + i);
    int4v v2 = *(const int4v*)(o2 + i);
    int4v ro;
#pragma unroll
    for (int k = 0; k < 4; ++k) {
      unsigned u1 = (unsigned)v1[k], u2 = (unsigned)v2[k];
      float lo = b2f((unsigned short)u1) * c1 + b2f((unsigned short)u2) * c2;
      float hi = b2f((unsigned short)(u1 >> 16)) * c1 + b2f((unsigned short)(u2 >> 16)) * c2;
      ro[k] = (int)pk2b(lo, hi);
    }
    *(int4v*)(o1 + i) = ro;
  }
}

// ---------------- launch ----------------

extern "C" void kernel_launch(void* const* d_in, const int* in_sizes, int n_in,
                              void* d_out, int out_size, void* d_ws, size_t ws_size,
                              hipStream_t stream) {
  (void)in_sizes; (void)n_in; (void)out_size; (void)ws_size;
  const float* x  = (const float*)d_in[0];
  const int*  tp  = (const int*)d_in[1];
  const float* Wq = (const float*)d_in[2];
  const float* Wk = (const float*)d_in[3];
  const float* Wv = (const float*)d_in[4];
  const float* Wo = (const float*)d_in[5];
  float* out = (float*)d_out;

  char* ws = (char*)d_ws;
  unsigned short* xb    = (unsigned short*)(ws);                       // 8MB
  unsigned short* Ob    = (unsigned short*)(ws);                       // reuses xb
  unsigned short* Wqkvb = (unsigned short*)(ws + (8ull << 20));        // 6MB
  unsigned short* P2    = (unsigned short*)(ws + (8ull << 20));        // reuses Wqkvb (4MB)
  unsigned short* Wob   = (unsigned short*)(ws + (14ull << 20));       // 2MB
  unsigned short* Qb    = (unsigned short*)(ws + (16ull << 20));       // 8MB
  unsigned short* Kb    = (unsigned short*)(ws + (24ull << 20));       // 8MB
  unsigned short* VbT   = (unsigned short*)(ws + (32ull << 20));       // 8MB
  float* cosT   = (float*)(ws + (40ull << 20));                        // 256KB
  float* sinT   = (float*)(ws + (40ull << 20) + 262144);               // 256KB
  float* stats1 = (float*)(ws + (40ull << 20));                        // reuses cosT
  float* stats2 = (float*)(ws + (40ull << 20) + 262144);               // reuses sinT

  prep_kernel<<<4128, 256, 0, stream>>>(x, Wq, Wk, Wv, Wo, tp, xb, Wqkvb, Wob, cosT, sinT);
  gemm_qkv_kernel<<<256, 512, 0, stream>>>(xb, Wqkvb, Qb, Kb, VbT, cosT, sinT);
  attn_kernel<<<dim3(32, 16), 256, 0, stream>>>(Qb, Kb, VbT, Ob, P2, stats1, stats2);
  merge_kernel<<<256, 256, 0, stream>>>(Ob, P2, stats1, stats2);
  gemm_out_kernel<<<256, 512, 0, stream>>>(Ob, Wob, out);
}